// Round 1
// baseline (610.685 us; speedup 1.0000x reference)
//
#include <hip/hip_runtime.h>

#define NN 50000
#define NE 800000
// F=64 hidden, 10 classes padded to 16

// ---------- dense linear: out[n][j] = sum_k H[n][k] * W[k][j], 64x64 ----------
__global__ __launch_bounds__(256) void lin64_kernel(const float* __restrict__ H,
                                                    const float* __restrict__ W,
                                                    float* __restrict__ out, int n_nodes) {
    int g = blockIdx.x * blockDim.x + threadIdx.x;
    int n = g >> 6, j = g & 63;
    if (n >= n_nodes) return;
    const float* hrow = H + (size_t)n * 64;
    float acc = 0.f;
#pragma unroll
    for (int k4 = 0; k4 < 16; ++k4) {
        float4 h = *reinterpret_cast<const float4*>(hrow + k4 * 4);
        acc += h.x * W[(k4 * 4 + 0) * 64 + j];
        acc += h.y * W[(k4 * 4 + 1) * 64 + j];
        acc += h.z * W[(k4 * 4 + 2) * 64 + j];
        acc += h.w * W[(k4 * 4 + 3) * 64 + j];
    }
    out[(size_t)n * 64 + j] = acc;
}

// ---------- linear to 10 classes, padded stride 16 ----------
__global__ __launch_bounds__(256) void lin16_kernel(const float* __restrict__ H,
                                                    const float* __restrict__ W2,
                                                    float* __restrict__ out, int n_nodes) {
    int g = blockIdx.x * blockDim.x + threadIdx.x;
    int n = g >> 4, j = g & 15;
    if (n >= n_nodes) return;
    float acc = 0.f;
    if (j < 10) {
        const float* hrow = H + (size_t)n * 64;
#pragma unroll
        for (int k = 0; k < 64; ++k) acc += hrow[k] * W2[k * 10 + j];
    }
    out[(size_t)n * 16 + j] = acc;  // padding lanes write 0
}

// ---------- edge aggregation, 64 features: wave per edge, lane per feature ----------
__global__ __launch_bounds__(256) void agg64_kernel(const float* __restrict__ hlin,
                                                    const int* __restrict__ src,
                                                    const int* __restrict__ dst,
                                                    const float* __restrict__ ew,
                                                    float* __restrict__ agg, int n_edges) {
    long g = (long)blockIdx.x * blockDim.x + threadIdx.x;
    if (g >= (long)n_edges * 64) return;
    int e = (int)(g >> 6), f = (int)(g & 63);
    int s = src[e], d = dst[e];
    float w = ew[e];
    atomicAdd(&agg[(size_t)d * 64 + f], hlin[(size_t)s * 64 + f] * w);
}

// ---------- edge aggregation, padded-16 features ----------
__global__ __launch_bounds__(256) void agg16_kernel(const float* __restrict__ hlin,
                                                    const int* __restrict__ src,
                                                    const int* __restrict__ dst,
                                                    const float* __restrict__ ew,
                                                    float* __restrict__ agg, int n_edges) {
    long g = (long)blockIdx.x * blockDim.x + threadIdx.x;
    if (g >= (long)n_edges * 16) return;
    int e = (int)(g >> 4), f = (int)(g & 15);
    int s = src[e], d = dst[e];
    float w = ew[e];
    atomicAdd(&agg[(size_t)d * 16 + f], hlin[(size_t)s * 16 + f] * w);
}

// ---------- bias + softmax over 64 features (wave = one row) ----------
__global__ __launch_bounds__(256) void softmax64_kernel(const float* __restrict__ agg,
                                                        const float* __restrict__ b,
                                                        float* __restrict__ out, int n_nodes) {
    int g = blockIdx.x * blockDim.x + threadIdx.x;
    int n = g >> 6, j = g & 63;
    if (n >= n_nodes) return;
    float v = agg[(size_t)n * 64 + j] + b[j];
    float m = v;
#pragma unroll
    for (int o = 32; o; o >>= 1) m = fmaxf(m, __shfl_xor(m, o, 64));
    float p = __expf(v - m);
    float s = p;
#pragma unroll
    for (int o = 32; o; o >>= 1) s += __shfl_xor(s, o, 64);
    out[(size_t)n * 64 + j] = p / s;
}

// ---------- bias + softmax over 10 classes (16-lane group = one row) ----------
__global__ __launch_bounds__(256) void softmax10_kernel(const float* __restrict__ agg,
                                                        const float* __restrict__ b,
                                                        float* __restrict__ out, int n_nodes) {
    int g = blockIdx.x * blockDim.x + threadIdx.x;
    int n = g >> 4, j = g & 15;
    if (n >= n_nodes) return;
    float v = (j < 10) ? (agg[(size_t)n * 16 + j] + b[j]) : -1e30f;
    float m = v;
#pragma unroll
    for (int o = 8; o; o >>= 1) m = fmaxf(m, __shfl_xor(m, o, 64));
    float p = (j < 10) ? __expf(v - m) : 0.f;
    float s = p;
#pragma unroll
    for (int o = 8; o; o >>= 1) s += __shfl_xor(s, o, 64);
    if (j < 10) out[(size_t)n * 10 + j] = p / s;
}

extern "C" void kernel_launch(void* const* d_in, const int* in_sizes, int n_in,
                              void* d_out, int out_size, void* d_ws, size_t ws_size,
                              hipStream_t stream) {
    const float* x  = (const float*)d_in[0];
    const int*   ei = (const int*)d_in[1];   // [2, NE] int32 (jax default downcasts int64)
    const float* ew = (const float*)d_in[2];
    const float* W0 = (const float*)d_in[3];
    const float* b0 = (const float*)d_in[4];
    const float* W1 = (const float*)d_in[5];
    const float* b1 = (const float*)d_in[6];
    const float* W2 = (const float*)d_in[7];
    const float* b2 = (const float*)d_in[8];
    float* out = (float*)d_out;

    const int* src = ei;
    const int* dst = ei + NE;

    char* ws = (char*)d_ws;
    const size_t SZ = (size_t)NN * 64 * sizeof(float);  // 12.8 MB
    float* A = (float*)ws;              // lin output
    float* B = (float*)(ws + SZ);       // agg accumulator
    float* C = (float*)(ws + 2 * SZ);   // softmax output (next layer input)

    const int gLin = (NN * 64 + 255) / 256;
    const int gAgg = (int)(((long)NE * 64 + 255) / 256);
    const int gL16 = (NN * 16 + 255) / 256;
    const int gA16 = (int)(((long)NE * 16 + 255) / 256);

    // ----- layer 0 -----
    lin64_kernel<<<gLin, 256, 0, stream>>>(x, W0, A, NN);
    hipMemsetAsync(B, 0, SZ, stream);
    agg64_kernel<<<gAgg, 256, 0, stream>>>(A, src, dst, ew, B, NE);
    softmax64_kernel<<<gLin, 256, 0, stream>>>(B, b0, C, NN);

    // ----- layer 1 -----
    lin64_kernel<<<gLin, 256, 0, stream>>>(C, W1, A, NN);
    hipMemsetAsync(B, 0, SZ, stream);
    agg64_kernel<<<gAgg, 256, 0, stream>>>(A, src, dst, ew, B, NE);
    softmax64_kernel<<<gLin, 256, 0, stream>>>(B, b1, C, NN);

    // ----- layer 2 (10 classes, padded to 16) -----
    lin16_kernel<<<gL16, 256, 0, stream>>>(C, W2, A, NN);
    hipMemsetAsync(B, 0, (size_t)NN * 16 * sizeof(float), stream);
    agg16_kernel<<<gA16, 256, 0, stream>>>(A, src, dst, ew, B, NE);
    softmax10_kernel<<<gL16, 256, 0, stream>>>(B, b2, out, NN);
}

// Round 3
// 565.676 us; speedup vs baseline: 1.0796x; 1.0796x over previous
//
#include <hip/hip_runtime.h>

#define NN 50000
#define NE 800000

// ============ CSR build ============
__global__ __launch_bounds__(256) void count_kernel(const int* __restrict__ dst,
                                                    int* __restrict__ cursor) {
    int e = blockIdx.x * 256 + threadIdx.x;
    if (e < NE) atomicAdd(&cursor[dst[e]], 1);
}

// single-block exclusive scan of 50k counts; writes offs[] and resets cursor[]=offs
__global__ __launch_bounds__(1024) void scan_kernel(int* __restrict__ cursor,
                                                    int* __restrict__ offs) {
    __shared__ int sm[1024];
    int t = threadIdx.x;
    const int CHUNK = (NN + 1023) / 1024;  // 49
    int base = t * CHUNK;
    int lim = NN - base;
    if (lim > CHUNK) lim = CHUNK;
    if (lim < 0) lim = 0;
    int sum = 0;
    for (int i = 0; i < lim; ++i) sum += cursor[base + i];
    sm[t] = sum;
    __syncthreads();
    for (int off = 1; off < 1024; off <<= 1) {
        int v = (t >= off) ? sm[t - off] : 0;
        __syncthreads();
        sm[t] += v;
        __syncthreads();
    }
    int run = sm[t] - sum;  // exclusive prefix
    for (int i = 0; i < lim; ++i) {
        int c = cursor[base + i];
        offs[base + i] = run;
        cursor[base + i] = run;
        run += c;
    }
    if (t == 1023) offs[NN] = sm[1023];
}

__global__ __launch_bounds__(256) void scatter_kernel(const int* __restrict__ src,
                                                      const int* __restrict__ dst,
                                                      const float* __restrict__ ew,
                                                      int* __restrict__ cursor,
                                                      int* __restrict__ esrc,
                                                      float* __restrict__ ewt) {
    int e = blockIdx.x * 256 + threadIdx.x;
    if (e >= NE) return;
    int d = dst[e];
    int pos = atomicAdd(&cursor[d], 1);
    esrc[pos] = src[e];
    ewt[pos] = ew[e];
}

// ============ dense linear 64x64 ============
__global__ __launch_bounds__(256) void lin64_kernel(const float* __restrict__ H,
                                                    const float* __restrict__ W,
                                                    float* __restrict__ out) {
    int g = blockIdx.x * 256 + threadIdx.x;
    int n = g >> 6, j = g & 63;
    if (n >= NN) return;
    const float* hrow = H + (size_t)n * 64;
    float acc = 0.f;
#pragma unroll
    for (int k4 = 0; k4 < 16; ++k4) {
        float4 h = *reinterpret_cast<const float4*>(hrow + k4 * 4);
        acc += h.x * W[(k4 * 4 + 0) * 64 + j];
        acc += h.y * W[(k4 * 4 + 1) * 64 + j];
        acc += h.z * W[(k4 * 4 + 2) * 64 + j];
        acc += h.w * W[(k4 * 4 + 3) * 64 + j];
    }
    out[(size_t)n * 64 + j] = acc;
}

// ============ linear 64 -> 10 (padded stride 16) ============
__global__ __launch_bounds__(256) void lin16_kernel(const float* __restrict__ H,
                                                    const float* __restrict__ W2,
                                                    float* __restrict__ out) {
    int g = blockIdx.x * 256 + threadIdx.x;
    int n = g >> 4, j = g & 15;
    if (n >= NN) return;
    float acc = 0.f;
    if (j < 10) {
        const float* hrow = H + (size_t)n * 64;
#pragma unroll
        for (int k = 0; k < 64; ++k) acc += hrow[k] * W2[k * 10 + j];
    }
    out[(size_t)n * 16 + j] = acc;
}

// ============ CSR aggregate + bias + softmax, 64 features (wave per node) ============
__global__ __launch_bounds__(256) void aggsm64_kernel(const float* __restrict__ h,
                                                      const int* __restrict__ offs,
                                                      const int* __restrict__ esrc,
                                                      const float* __restrict__ ewt,
                                                      const float* __restrict__ b,
                                                      float* __restrict__ out) {
    int g = blockIdx.x * 256 + threadIdx.x;
    int n = g >> 6, lane = g & 63;
    if (n >= NN) return;
    int beg = offs[n], end = offs[n + 1];
    float acc = 0.f;
    for (int i = beg; i < end; ++i) {
        int s = esrc[i];
        float w = ewt[i];
        acc += h[(size_t)s * 64 + lane] * w;
    }
    float v = acc + b[lane];
    float m = v;
#pragma unroll
    for (int o = 32; o; o >>= 1) m = fmaxf(m, __shfl_xor(m, o, 64));
    float p = __expf(v - m);
    float s2 = p;
#pragma unroll
    for (int o = 32; o; o >>= 1) s2 += __shfl_xor(s2, o, 64);
    out[(size_t)n * 64 + lane] = p / s2;
}

// ============ CSR aggregate + bias + softmax, 10 classes (16-lane group per node) ============
__global__ __launch_bounds__(256) void aggsm10_kernel(const float* __restrict__ h,
                                                      const int* __restrict__ offs,
                                                      const int* __restrict__ esrc,
                                                      const float* __restrict__ ewt,
                                                      const float* __restrict__ b,
                                                      float* __restrict__ out) {
    int g = blockIdx.x * 256 + threadIdx.x;
    int n = g >> 4, j = g & 15;
    if (n >= NN) return;
    int beg = offs[n], end = offs[n + 1];
    float acc = 0.f;
    for (int i = beg; i < end; ++i) {
        int s = esrc[i];
        float w = ewt[i];
        acc += h[(size_t)s * 16 + j] * w;
    }
    float v = (j < 10) ? (acc + b[j]) : -1e30f;
    float m = v;
#pragma unroll
    for (int o = 8; o; o >>= 1) m = fmaxf(m, __shfl_xor(m, o, 64));
    float p = (j < 10) ? __expf(v - m) : 0.f;
    float s2 = p;
#pragma unroll
    for (int o = 8; o; o >>= 1) s2 += __shfl_xor(s2, o, 64);
    if (j < 10) out[(size_t)n * 10 + j] = p / s2;
}

extern "C" void kernel_launch(void* const* d_in, const int* in_sizes, int n_in,
                              void* d_out, int out_size, void* d_ws, size_t ws_size,
                              hipStream_t stream) {
    const float* x  = (const float*)d_in[0];
    const int*   ei = (const int*)d_in[1];
    const float* ew = (const float*)d_in[2];
    const float* W0 = (const float*)d_in[3];
    const float* b0 = (const float*)d_in[4];
    const float* W1 = (const float*)d_in[5];
    const float* b1 = (const float*)d_in[6];
    const float* W2 = (const float*)d_in[7];
    const float* b2 = (const float*)d_in[8];
    float* out = (float*)d_out;

    const int* src = ei;
    const int* dst = ei + NE;

    // workspace layout
    char* ws = (char*)d_ws;
    const size_t SZ = (size_t)NN * 64 * sizeof(float);        // 12.8 MB
    float* A      = (float*)ws;                               // lin output
    float* C      = (float*)(ws + SZ);                        // act output
    int*   esrc   = (int*)(ws + 2 * SZ);                      // 3.2 MB
    float* ewt    = (float*)(ws + 2 * SZ + (size_t)NE * 4);   // 3.2 MB
    int*   offs   = (int*)(ws + 2 * SZ + (size_t)NE * 8);     // (NN+1)*4
    int*   cursor = offs + (NN + 1);                          // NN*4

    const int gE   = (NE + 255) / 256;         // 3125
    const int gN64 = (NN * 64 + 255) / 256;    // 12500
    const int gN16 = (NN * 16 + 255) / 256;    // 3125

    // ----- CSR build (graph shared by all 3 layers) -----
    hipMemsetAsync(cursor, 0, (size_t)NN * sizeof(int), stream);
    count_kernel<<<gE, 256, 0, stream>>>(dst, cursor);
    scan_kernel<<<1, 1024, 0, stream>>>(cursor, offs);
    scatter_kernel<<<gE, 256, 0, stream>>>(src, dst, ew, cursor, esrc, ewt);

    // ----- layer 0 -----
    lin64_kernel<<<gN64, 256, 0, stream>>>(x, W0, A);
    aggsm64_kernel<<<gN64, 256, 0, stream>>>(A, offs, esrc, ewt, b0, C);

    // ----- layer 1 -----
    lin64_kernel<<<gN64, 256, 0, stream>>>(C, W1, A);
    aggsm64_kernel<<<gN64, 256, 0, stream>>>(A, offs, esrc, ewt, b1, C);

    // ----- layer 2 (10 classes, padded to 16) -----
    lin16_kernel<<<gN16, 256, 0, stream>>>(C, W2, A);
    aggsm10_kernel<<<gN16, 256, 0, stream>>>(A, offs, esrc, ewt, b2, out);
}

// Round 4
// 411.373 us; speedup vs baseline: 1.4845x; 1.3751x over previous
//
#include <hip/hip_runtime.h>

#define NN 50000
#define NE 800000

// ============ CSR build ============
__global__ __launch_bounds__(256) void count_kernel(const int* __restrict__ dst,
                                                    int* __restrict__ cursor) {
    int e = blockIdx.x * 256 + threadIdx.x;
    if (e < NE) atomicAdd(&cursor[dst[e]], 1);
}

// phase 1: 25 blocks x 256 thr, each block scans 2048 counts -> per-element
// block-local exclusive partials in offs[], block total in bsum[]
__global__ __launch_bounds__(256) void scan1_kernel(const int* __restrict__ cnt,
                                                    int* __restrict__ offs,
                                                    int* __restrict__ bsum) {
    __shared__ int sm[256];
    int b = blockIdx.x, t = threadIdx.x;
    int base = b * 2048 + t * 8;
    int v[8];
    int s = 0;
#pragma unroll
    for (int i = 0; i < 8; ++i) {
        int idx = base + i;
        int c = (idx < NN) ? cnt[idx] : 0;
        v[i] = s;  // thread-local exclusive prefix
        s += c;
    }
    sm[t] = s;
    __syncthreads();
    // inclusive Hillis-Steele over thread sums
    for (int off = 1; off < 256; off <<= 1) {
        int y = (t >= off) ? sm[t - off] : 0;
        __syncthreads();
        sm[t] += y;
        __syncthreads();
    }
    int excl = sm[t] - s;  // exclusive prefix of this thread within block
#pragma unroll
    for (int i = 0; i < 8; ++i) {
        int idx = base + i;
        if (idx < NN) offs[idx] = excl + v[i];
    }
    if (t == 255) bsum[b] = sm[255];
}

// phase 2: tiny serial scan of 25 block sums
__global__ __launch_bounds__(64) void scan2_kernel(const int* __restrict__ bsum,
                                                   int* __restrict__ bscan) {
    if (threadIdx.x == 0) {
        int run = 0;
        for (int k = 0; k < 25; ++k) {
            bscan[k] = run;
            run += bsum[k];
        }
    }
}

// phase 3: add block offsets, init cursor, write offs[NN]
__global__ __launch_bounds__(256) void scan3_kernel(int* __restrict__ offs,
                                                    const int* __restrict__ bscan,
                                                    int* __restrict__ cursor) {
    int i = blockIdx.x * 256 + threadIdx.x;
    if (i < NN) {
        int v = offs[i] + bscan[i >> 11];
        offs[i] = v;
        cursor[i] = v;
    }
    if (i == 0) offs[NN] = NE;
}

__global__ __launch_bounds__(256) void scatter_kernel(const int* __restrict__ src,
                                                      const int* __restrict__ dst,
                                                      const float* __restrict__ ew,
                                                      int* __restrict__ cursor,
                                                      int2* __restrict__ epair) {
    int e = blockIdx.x * 256 + threadIdx.x;
    if (e >= NE) return;
    int d = dst[e];
    int pos = atomicAdd(&cursor[d], 1);
    epair[pos] = make_int2(src[e], __float_as_int(ew[e]));
}

// ============ dense linear 64x64 ============
__global__ __launch_bounds__(256) void lin64_kernel(const float* __restrict__ H,
                                                    const float* __restrict__ W,
                                                    float* __restrict__ out) {
    int g = blockIdx.x * 256 + threadIdx.x;
    int n = g >> 6, j = g & 63;
    if (n >= NN) return;
    const float* hrow = H + (size_t)n * 64;
    float acc = 0.f;
#pragma unroll
    for (int k4 = 0; k4 < 16; ++k4) {
        float4 h = *reinterpret_cast<const float4*>(hrow + k4 * 4);
        acc += h.x * W[(k4 * 4 + 0) * 64 + j];
        acc += h.y * W[(k4 * 4 + 1) * 64 + j];
        acc += h.z * W[(k4 * 4 + 2) * 64 + j];
        acc += h.w * W[(k4 * 4 + 3) * 64 + j];
    }
    out[(size_t)n * 64 + j] = acc;
}

// ============ linear 64 -> 10 (padded stride 16) ============
__global__ __launch_bounds__(256) void lin16_kernel(const float* __restrict__ H,
                                                    const float* __restrict__ W2,
                                                    float* __restrict__ out) {
    int g = blockIdx.x * 256 + threadIdx.x;
    int n = g >> 4, j = g & 15;
    if (n >= NN) return;
    float acc = 0.f;
    if (j < 10) {
        const float* hrow = H + (size_t)n * 64;
#pragma unroll
        for (int k = 0; k < 64; ++k) acc += hrow[k] * W2[k * 10 + j];
    }
    out[(size_t)n * 16 + j] = acc;
}

// ============ CSR aggregate + bias + softmax, 64 features (wave per node) ============
__global__ __launch_bounds__(256) void aggsm64_kernel(const float* __restrict__ h,
                                                      const int* __restrict__ offs,
                                                      const int2* __restrict__ epair,
                                                      const float* __restrict__ b,
                                                      float* __restrict__ out) {
    int g = blockIdx.x * 256 + threadIdx.x;
    int n = g >> 6, lane = g & 63;
    if (n >= NN) return;
    int beg = offs[n], end = offs[n + 1];
    float acc = 0.f;
    int i = beg;
    // 2-edge unroll for memory-level parallelism
    for (; i + 1 < end; i += 2) {
        int2 p0 = epair[i];
        int2 p1 = epair[i + 1];
        float h0 = h[(size_t)p0.x * 64 + lane];
        float h1 = h[(size_t)p1.x * 64 + lane];
        acc += h0 * __int_as_float(p0.y);
        acc += h1 * __int_as_float(p1.y);
    }
    if (i < end) {
        int2 p0 = epair[i];
        acc += h[(size_t)p0.x * 64 + lane] * __int_as_float(p0.y);
    }
    float v = acc + b[lane];
    float m = v;
#pragma unroll
    for (int o = 32; o; o >>= 1) m = fmaxf(m, __shfl_xor(m, o, 64));
    float p = __expf(v - m);
    float s2 = p;
#pragma unroll
    for (int o = 32; o; o >>= 1) s2 += __shfl_xor(s2, o, 64);
    out[(size_t)n * 64 + lane] = p / s2;
}

// ============ CSR aggregate + bias + softmax, 10 classes (16-lane group per node) ============
__global__ __launch_bounds__(256) void aggsm10_kernel(const float* __restrict__ h,
                                                      const int* __restrict__ offs,
                                                      const int2* __restrict__ epair,
                                                      const float* __restrict__ b,
                                                      float* __restrict__ out) {
    int g = blockIdx.x * 256 + threadIdx.x;
    int n = g >> 4, j = g & 15;
    if (n >= NN) return;
    int beg = offs[n], end = offs[n + 1];
    float acc = 0.f;
    int i = beg;
    for (; i + 1 < end; i += 2) {
        int2 p0 = epair[i];
        int2 p1 = epair[i + 1];
        float h0 = h[(size_t)p0.x * 16 + j];
        float h1 = h[(size_t)p1.x * 16 + j];
        acc += h0 * __int_as_float(p0.y);
        acc += h1 * __int_as_float(p1.y);
    }
    if (i < end) {
        int2 p0 = epair[i];
        acc += h[(size_t)p0.x * 16 + j] * __int_as_float(p0.y);
    }
    float v = (j < 10) ? (acc + b[j]) : -1e30f;
    float m = v;
#pragma unroll
    for (int o = 8; o; o >>= 1) m = fmaxf(m, __shfl_xor(m, o, 64));
    float p = (j < 10) ? __expf(v - m) : 0.f;
    float s2 = p;
#pragma unroll
    for (int o = 8; o; o >>= 1) s2 += __shfl_xor(s2, o, 64);
    if (j < 10) out[(size_t)n * 10 + j] = p / s2;
}

extern "C" void kernel_launch(void* const* d_in, const int* in_sizes, int n_in,
                              void* d_out, int out_size, void* d_ws, size_t ws_size,
                              hipStream_t stream) {
    const float* x  = (const float*)d_in[0];
    const int*   ei = (const int*)d_in[1];
    const float* ew = (const float*)d_in[2];
    const float* W0 = (const float*)d_in[3];
    const float* b0 = (const float*)d_in[4];
    const float* W1 = (const float*)d_in[5];
    const float* b1 = (const float*)d_in[6];
    const float* W2 = (const float*)d_in[7];
    const float* b2 = (const float*)d_in[8];
    float* out = (float*)d_out;

    const int* src = ei;
    const int* dst = ei + NE;

    // workspace layout (8B-aligned segments)
    char* ws = (char*)d_ws;
    const size_t SZ = (size_t)NN * 64 * sizeof(float);        // 12.8 MB
    float* A      = (float*)ws;                               // lin output
    float* C      = (float*)(ws + SZ);                        // act output
    int2*  epair  = (int2*)(ws + 2 * SZ);                     // 6.4 MB
    int*   offs   = (int*)(ws + 2 * SZ + (size_t)NE * 8);     // (NN+1)*4
    int*   cursor = offs + (NN + 1);                          // NN*4
    int*   bsum   = cursor + NN;                              // 32*4
    int*   bscan  = bsum + 32;                                // 32*4

    const int gE   = (NE + 255) / 256;         // 3125
    const int gN   = (NN + 255) / 256;         // 196
    const int gN64 = (NN * 64 + 255) / 256;    // 12500
    const int gN16 = (NN * 16 + 255) / 256;    // 3125

    // ----- CSR build (graph shared by all 3 layers) -----
    hipMemsetAsync(cursor, 0, (size_t)NN * sizeof(int), stream);
    count_kernel<<<gE, 256, 0, stream>>>(dst, cursor);
    scan1_kernel<<<25, 256, 0, stream>>>(cursor, offs, bsum);
    scan2_kernel<<<1, 64, 0, stream>>>(bsum, bscan);
    scan3_kernel<<<gN, 256, 0, stream>>>(offs, bscan, cursor);
    scatter_kernel<<<gE, 256, 0, stream>>>(src, dst, ew, cursor, epair);

    // ----- layer 0 -----
    lin64_kernel<<<gN64, 256, 0, stream>>>(x, W0, A);
    aggsm64_kernel<<<gN64, 256, 0, stream>>>(A, offs, epair, b0, C);

    // ----- layer 1 -----
    lin64_kernel<<<gN64, 256, 0, stream>>>(C, W1, A);
    aggsm64_kernel<<<gN64, 256, 0, stream>>>(A, offs, epair, b1, C);

    // ----- layer 2 (10 classes, padded to 16) -----
    lin16_kernel<<<gN16, 256, 0, stream>>>(C, W2, A);
    aggsm10_kernel<<<gN16, 256, 0, stream>>>(A, offs, epair, b2, out);
}

// Round 6
// 382.556 us; speedup vs baseline: 1.5963x; 1.0753x over previous
//
#include <hip/hip_runtime.h>

#define NN 50000
#define NE 800000

// ============ CSR build ============
__global__ __launch_bounds__(256) void count_kernel(const int* __restrict__ dst,
                                                    int* __restrict__ cursor) {
    int e = blockIdx.x * 256 + threadIdx.x;
    if (e < NE) atomicAdd(&cursor[dst[e]], 1);
}

// phase 1: 25 blocks x 256 thr, each block scans 2048 counts
__global__ __launch_bounds__(256) void scan1_kernel(const int* __restrict__ cnt,
                                                    int* __restrict__ offs,
                                                    int* __restrict__ bsum) {
    __shared__ int sm[256];
    int b = blockIdx.x, t = threadIdx.x;
    int base = b * 2048 + t * 8;
    int v[8];
    int s = 0;
#pragma unroll
    for (int i = 0; i < 8; ++i) {
        int idx = base + i;
        int c = (idx < NN) ? cnt[idx] : 0;
        v[i] = s;
        s += c;
    }
    sm[t] = s;
    __syncthreads();
    for (int off = 1; off < 256; off <<= 1) {
        int y = (t >= off) ? sm[t - off] : 0;
        __syncthreads();
        sm[t] += y;
        __syncthreads();
    }
    int excl = sm[t] - s;
#pragma unroll
    for (int i = 0; i < 8; ++i) {
        int idx = base + i;
        if (idx < NN) offs[idx] = excl + v[i];
    }
    if (t == 255) bsum[b] = sm[255];
}

__global__ __launch_bounds__(64) void scan2_kernel(const int* __restrict__ bsum,
                                                   int* __restrict__ bscan) {
    if (threadIdx.x == 0) {
        int run = 0;
        for (int k = 0; k < 25; ++k) {
            bscan[k] = run;
            run += bsum[k];
        }
    }
}

__global__ __launch_bounds__(256) void scan3_kernel(int* __restrict__ offs,
                                                    const int* __restrict__ bscan,
                                                    int* __restrict__ cursor) {
    int i = blockIdx.x * 256 + threadIdx.x;
    if (i < NN) {
        int v = offs[i] + bscan[i >> 11];
        offs[i] = v;
        cursor[i] = v;
    }
    if (i == 0) offs[NN] = NE;
}

__global__ __launch_bounds__(256) void scatter_kernel(const int* __restrict__ src,
                                                      const int* __restrict__ dst,
                                                      const float* __restrict__ ew,
                                                      int* __restrict__ cursor,
                                                      int2* __restrict__ epair) {
    int e = blockIdx.x * 256 + threadIdx.x;
    if (e >= NE) return;
    int d = dst[e];
    int pos = atomicAdd(&cursor[d], 1);
    epair[pos] = make_int2(src[e], __float_as_int(ew[e]));
}

// ============ fused layer A: out = softmax(agg(h) @ W + b), 64-dim ============
// wave per node, lane = feature. agg(h)@W == agg(h@W) by linearity.
__global__ __launch_bounds__(256) void fusedA_kernel(const float* __restrict__ h,
                                                     const int* __restrict__ offs,
                                                     const int2* __restrict__ epair,
                                                     const float* __restrict__ W,
                                                     const float* __restrict__ b,
                                                     float* __restrict__ out) {
    __shared__ float Wl[4096];  // 16 KB
    int tid = threadIdx.x;
    for (int i = tid; i < 1024; i += 256)
        reinterpret_cast<float4*>(Wl)[i] = reinterpret_cast<const float4*>(W)[i];
    __syncthreads();

    int g = blockIdx.x * 256 + tid;
    int n = g >> 6, lane = g & 63;
    if (n >= NN) return;
    int beg = offs[n], end = offs[n + 1];
    float acc = 0.f;
    int i = beg;
    for (; i + 3 < end; i += 4) {
        int2 p0 = epair[i], p1 = epair[i + 1], p2 = epair[i + 2], p3 = epair[i + 3];
        float h0 = h[(size_t)p0.x * 64 + lane];
        float h1 = h[(size_t)p1.x * 64 + lane];
        float h2 = h[(size_t)p2.x * 64 + lane];
        float h3 = h[(size_t)p3.x * 64 + lane];
        acc = fmaf(h0, __int_as_float(p0.y), acc);
        acc = fmaf(h1, __int_as_float(p1.y), acc);
        acc = fmaf(h2, __int_as_float(p2.y), acc);
        acc = fmaf(h3, __int_as_float(p3.y), acc);
    }
    for (; i < end; ++i) {
        int2 p0 = epair[i];
        acc = fmaf(h[(size_t)p0.x * 64 + lane], __int_as_float(p0.y), acc);
    }

    // matvec: y_lane = sum_k acc_k * W[k][lane]
    float y = 0.f;
#pragma unroll
    for (int k = 0; k < 64; ++k)
        y = fmaf(__shfl(acc, k, 64), Wl[k * 64 + lane], y);
    y += b[lane];

    // softmax over 64
    float m = y;
#pragma unroll
    for (int o = 32; o; o >>= 1) m = fmaxf(m, __shfl_xor(m, o, 64));
    float p = __expf(y - m);
    float s2 = p;
#pragma unroll
    for (int o = 32; o; o >>= 1) s2 += __shfl_xor(s2, o, 64);
    out[(size_t)n * 64 + lane] = p / s2;
}

// ============ fused layer B: h2 = softmax(agg(h)@W1+b1); write u2 = h2@W2 (64->10 pad16) ============
__global__ __launch_bounds__(256) void fusedB_kernel(const float* __restrict__ h,
                                                     const int* __restrict__ offs,
                                                     const int2* __restrict__ epair,
                                                     const float* __restrict__ W1,
                                                     const float* __restrict__ b1,
                                                     const float* __restrict__ W2,
                                                     float* __restrict__ u2out) {
    __shared__ float Wl[4096];   // 16 KB
    __shared__ float W2l[1024];  // 64 x 16 padded, 4 KB
    int tid = threadIdx.x;
    for (int i = tid; i < 1024; i += 256)
        reinterpret_cast<float4*>(Wl)[i] = reinterpret_cast<const float4*>(W1)[i];
    for (int i = tid; i < 1024; i += 256) {
        int k = i >> 4, m = i & 15;
        W2l[i] = (m < 10) ? W2[k * 10 + m] : 0.f;
    }
    __syncthreads();

    int g = blockIdx.x * 256 + tid;
    int n = g >> 6, lane = g & 63;
    if (n >= NN) return;
    int beg = offs[n], end = offs[n + 1];
    float acc = 0.f;
    int i = beg;
    for (; i + 3 < end; i += 4) {
        int2 p0 = epair[i], p1 = epair[i + 1], p2 = epair[i + 2], p3 = epair[i + 3];
        float h0 = h[(size_t)p0.x * 64 + lane];
        float h1 = h[(size_t)p1.x * 64 + lane];
        float h2 = h[(size_t)p2.x * 64 + lane];
        float h3 = h[(size_t)p3.x * 64 + lane];
        acc = fmaf(h0, __int_as_float(p0.y), acc);
        acc = fmaf(h1, __int_as_float(p1.y), acc);
        acc = fmaf(h2, __int_as_float(p2.y), acc);
        acc = fmaf(h3, __int_as_float(p3.y), acc);
    }
    for (; i < end; ++i) {
        int2 p0 = epair[i];
        acc = fmaf(h[(size_t)p0.x * 64 + lane], __int_as_float(p0.y), acc);
    }

    float y = 0.f;
#pragma unroll
    for (int k = 0; k < 64; ++k)
        y = fmaf(__shfl(acc, k, 64), Wl[k * 64 + lane], y);
    y += b1[lane];

    float m = y;
#pragma unroll
    for (int o = 32; o; o >>= 1) m = fmaxf(m, __shfl_xor(m, o, 64));
    float p = __expf(y - m);
    float s2 = p;
#pragma unroll
    for (int o = 32; o; o >>= 1) s2 += __shfl_xor(s2, o, 64);
    float h2v = p / s2;  // softmax output, lane j

    // u2[m] = sum_k h2_k * W2[k][m]  (lanes 0..15 produce the padded row)
    float u = 0.f;
    int mm = lane & 15;
#pragma unroll
    for (int k = 0; k < 64; ++k)
        u = fmaf(__shfl(h2v, k, 64), W2l[k * 16 + mm], u);
    if (lane < 16) u2out[(size_t)n * 16 + lane] = u;
}

// ============ final: out = softmax(agg(u2) + b2), 10 classes ============
__global__ __launch_bounds__(256) void aggsm10_kernel(const float* __restrict__ u2,
                                                      const int* __restrict__ offs,
                                                      const int2* __restrict__ epair,
                                                      const float* __restrict__ b,
                                                      float* __restrict__ out) {
    int g = blockIdx.x * 256 + threadIdx.x;
    int n = g >> 4, j = g & 15;
    if (n >= NN) return;
    int beg = offs[n], end = offs[n + 1];
    float acc = 0.f;
    int i = beg;
    for (; i + 1 < end; i += 2) {
        int2 p0 = epair[i];
        int2 p1 = epair[i + 1];
        float h0 = u2[(size_t)p0.x * 16 + j];
        float h1 = u2[(size_t)p1.x * 16 + j];
        acc = fmaf(h0, __int_as_float(p0.y), acc);
        acc = fmaf(h1, __int_as_float(p1.y), acc);
    }
    if (i < end) {
        int2 p0 = epair[i];
        acc = fmaf(u2[(size_t)p0.x * 16 + j], __int_as_float(p0.y), acc);
    }
    float v = (j < 10) ? (acc + b[j]) : -1e30f;
    float m = v;
#pragma unroll
    for (int o = 8; o; o >>= 1) m = fmaxf(m, __shfl_xor(m, o, 64));
    float p = (j < 10) ? __expf(v - m) : 0.f;
    float s2 = p;
#pragma unroll
    for (int o = 8; o; o >>= 1) s2 += __shfl_xor(s2, o, 64);
    if (j < 10) out[(size_t)n * 10 + j] = p / s2;
}

extern "C" void kernel_launch(void* const* d_in, const int* in_sizes, int n_in,
                              void* d_out, int out_size, void* d_ws, size_t ws_size,
                              hipStream_t stream) {
    const float* x  = (const float*)d_in[0];
    const int*   ei = (const int*)d_in[1];
    const float* ew = (const float*)d_in[2];
    const float* W0 = (const float*)d_in[3];
    const float* b0 = (const float*)d_in[4];
    const float* W1 = (const float*)d_in[5];
    const float* b1 = (const float*)d_in[6];
    const float* W2 = (const float*)d_in[7];
    const float* b2 = (const float*)d_in[8];
    float* out = (float*)d_out;

    const int* src = ei;
    const int* dst = ei + NE;

    char* ws = (char*)d_ws;
    const size_t SZ = (size_t)NN * 64 * sizeof(float);        // 12.8 MB
    float* C      = (float*)ws;                               // layer-0 output h1
    float* U      = (float*)(ws + SZ);                        // u2 (padded 16), 3.2 MB
    int2*  epair  = (int2*)(ws + SZ + (size_t)NN * 16 * 4);   // 6.4 MB
    char*  tail   = ws + SZ + (size_t)NN * 16 * 4 + (size_t)NE * 8;
    int*   offs   = (int*)tail;                               // (NN+1)*4
    int*   cursor = offs + (NN + 1);                          // NN*4
    int*   bsum   = cursor + NN;                              // 32*4
    int*   bscan  = bsum + 32;                                // 32*4

    const int gE   = (NE + 255) / 256;         // 3125
    const int gN   = (NN + 255) / 256;         // 196
    const int gN64 = (NN * 64 + 255) / 256;    // 12500
    const int gN16 = (NN * 16 + 255) / 256;    // 3125

    // ----- CSR build -----
    hipMemsetAsync(cursor, 0, (size_t)NN * sizeof(int), stream);
    count_kernel<<<gE, 256, 0, stream>>>(dst, cursor);
    scan1_kernel<<<25, 256, 0, stream>>>(cursor, offs, bsum);
    scan2_kernel<<<1, 64, 0, stream>>>(bsum, bscan);
    scan3_kernel<<<gN, 256, 0, stream>>>(offs, bscan, cursor);
    scatter_kernel<<<gE, 256, 0, stream>>>(src, dst, ew, cursor, epair);

    // ----- layer 0: h1 = softmax(agg(x)@W0 + b0) -----
    fusedA_kernel<<<gN64, 256, 0, stream>>>(x, offs, epair, W0, b0, C);

    // ----- layer 1 (+ layer-2 linear): u2 = softmax(agg(h1)@W1 + b1) @ W2 -----
    fusedB_kernel<<<gN64, 256, 0, stream>>>(C, offs, epair, W1, b1, W2, U);

    // ----- layer 2: out = softmax(agg(u2) + b2) -----
    aggsm10_kernel<<<gN16, 256, 0, stream>>>(U, offs, epair, b2, out);
}

// Round 9
// 318.935 us; speedup vs baseline: 1.9148x; 1.1995x over previous
//
#include <hip/hip_runtime.h>

#define NN 50000
#define NE 800000

// ============ CSR build ============
__global__ __launch_bounds__(256) void count_kernel(const int* __restrict__ dst,
                                                    int* __restrict__ cursor) {
    int e = blockIdx.x * 256 + threadIdx.x;
    if (e < NE) atomicAdd(&cursor[dst[e]], 1);
}

// phase 1: 25 blocks x 256 thr, each block scans 2048 counts
__global__ __launch_bounds__(256) void scan1_kernel(const int* __restrict__ cnt,
                                                    int* __restrict__ offs,
                                                    int* __restrict__ bsum) {
    __shared__ int sm[256];
    int b = blockIdx.x, t = threadIdx.x;
    int base = b * 2048 + t * 8;
    int v[8];
    int s = 0;
#pragma unroll
    for (int i = 0; i < 8; ++i) {
        int idx = base + i;
        int c = (idx < NN) ? cnt[idx] : 0;
        v[i] = s;
        s += c;
    }
    sm[t] = s;
    __syncthreads();
    for (int off = 1; off < 256; off <<= 1) {
        int y = (t >= off) ? sm[t - off] : 0;
        __syncthreads();
        sm[t] += y;
        __syncthreads();
    }
    int excl = sm[t] - s;
#pragma unroll
    for (int i = 0; i < 8; ++i) {
        int idx = base + i;
        if (idx < NN) offs[idx] = excl + v[i];
    }
    if (t == 255) bsum[b] = sm[255];
}

__global__ __launch_bounds__(64) void scan2_kernel(const int* __restrict__ bsum,
                                                   int* __restrict__ bscan) {
    if (threadIdx.x == 0) {
        int run = 0;
        for (int k = 0; k < 25; ++k) {
            bscan[k] = run;
            run += bsum[k];
        }
    }
}

__global__ __launch_bounds__(256) void scan3_kernel(int* __restrict__ offs,
                                                    const int* __restrict__ bscan,
                                                    int* __restrict__ cursor) {
    int i = blockIdx.x * 256 + threadIdx.x;
    if (i < NN) {
        int v = offs[i] + bscan[i >> 11];
        offs[i] = v;
        cursor[i] = v;
    }
    if (i == 0) offs[NN] = NE;
}

__global__ __launch_bounds__(256) void scatter_kernel(const int* __restrict__ src,
                                                      const int* __restrict__ dst,
                                                      const float* __restrict__ ew,
                                                      int* __restrict__ cursor,
                                                      int2* __restrict__ epair) {
    int e = blockIdx.x * 256 + threadIdx.x;
    if (e >= NE) return;
    int d = dst[e];
    int pos = atomicAdd(&cursor[d], 1);
    epair[pos] = make_int2(src[e], __float_as_int(ew[e]));
}

// ============ fused 64-dim layer: out = softmax(agg(h) @ W + b) ============
// wave per node, lane = feature. agg(h)@W == agg(h@W) by linearity.
// matvec broadcast via v_readlane (VALU->SGPR, zero LDS traffic).
__global__ __launch_bounds__(256) void fusedA_kernel(const float* __restrict__ h,
                                                     const int* __restrict__ offs,
                                                     const int2* __restrict__ epair,
                                                     const float* __restrict__ W,
                                                     const float* __restrict__ b,
                                                     float* __restrict__ out) {
    __shared__ float Wl[4096];  // 16 KB
    int tid = threadIdx.x;
    for (int i = tid; i < 1024; i += 256)
        reinterpret_cast<float4*>(Wl)[i] = reinterpret_cast<const float4*>(W)[i];
    __syncthreads();

    int g = blockIdx.x * 256 + tid;
    int n = g >> 6, lane = g & 63;
    if (n >= NN) return;
    int beg = offs[n], end = offs[n + 1];
    float acc = 0.f;
    int i = beg;
    for (; i + 3 < end; i += 4) {
        int2 p0 = epair[i], p1 = epair[i + 1], p2 = epair[i + 2], p3 = epair[i + 3];
        float h0 = h[(size_t)p0.x * 64 + lane];
        float h1 = h[(size_t)p1.x * 64 + lane];
        float h2 = h[(size_t)p2.x * 64 + lane];
        float h3 = h[(size_t)p3.x * 64 + lane];
        acc = fmaf(h0, __int_as_float(p0.y), acc);
        acc = fmaf(h1, __int_as_float(p1.y), acc);
        acc = fmaf(h2, __int_as_float(p2.y), acc);
        acc = fmaf(h3, __int_as_float(p3.y), acc);
    }
    for (; i < end; ++i) {
        int2 p0 = epair[i];
        acc = fmaf(h[(size_t)p0.x * 64 + lane], __int_as_float(p0.y), acc);
    }

    // matvec: y_lane = sum_k acc_k * W[k][lane]; acc_k broadcast via readlane,
    // 4 split accumulators to break the fma dependency chain.
    int ai = __float_as_int(acc);
    float y0 = 0.f, y1 = 0.f, y2 = 0.f, y3 = 0.f;
#pragma unroll
    for (int k = 0; k < 64; k += 4) {
        float a0 = __int_as_float(__builtin_amdgcn_readlane(ai, k));
        float a1 = __int_as_float(__builtin_amdgcn_readlane(ai, k + 1));
        float a2 = __int_as_float(__builtin_amdgcn_readlane(ai, k + 2));
        float a3 = __int_as_float(__builtin_amdgcn_readlane(ai, k + 3));
        y0 = fmaf(a0, Wl[(k + 0) * 64 + lane], y0);
        y1 = fmaf(a1, Wl[(k + 1) * 64 + lane], y1);
        y2 = fmaf(a2, Wl[(k + 2) * 64 + lane], y2);
        y3 = fmaf(a3, Wl[(k + 3) * 64 + lane], y3);
    }
    float y = (y0 + y1) + (y2 + y3) + b[lane];

    // softmax over 64
    float m = y;
#pragma unroll
    for (int o = 32; o; o >>= 1) m = fmaxf(m, __shfl_xor(m, o, 64));
    float p = __expf(y - m);
    float s2 = p;
#pragma unroll
    for (int o = 32; o; o >>= 1) s2 += __shfl_xor(s2, o, 64);
    out[(size_t)n * 64 + lane] = p / s2;
}

// ============ linear 64 -> 10 (padded stride 16) ============
__global__ __launch_bounds__(256) void lin16_kernel(const float* __restrict__ H,
                                                    const float* __restrict__ W2,
                                                    float* __restrict__ out) {
    int g = blockIdx.x * 256 + threadIdx.x;
    int n = g >> 4, j = g & 15;
    if (n >= NN) return;
    float acc = 0.f;
    if (j < 10) {
        const float* hrow = H + (size_t)n * 64;
#pragma unroll
        for (int k = 0; k < 64; ++k) acc += hrow[k] * W2[k * 10 + j];
    }
    out[(size_t)n * 16 + j] = acc;
}

// ============ final: out = softmax(agg(u2) + b2), 10 classes ============
__global__ __launch_bounds__(256) void aggsm10_kernel(const float* __restrict__ u2,
                                                      const int* __restrict__ offs,
                                                      const int2* __restrict__ epair,
                                                      const float* __restrict__ b,
                                                      float* __restrict__ out) {
    int g = blockIdx.x * 256 + threadIdx.x;
    int n = g >> 4, j = g & 15;
    if (n >= NN) return;
    int beg = offs[n], end = offs[n + 1];
    float acc = 0.f;
    int i = beg;
    for (; i + 1 < end; i += 2) {
        int2 p0 = epair[i];
        int2 p1 = epair[i + 1];
        float h0 = u2[(size_t)p0.x * 16 + j];
        float h1 = u2[(size_t)p1.x * 16 + j];
        acc = fmaf(h0, __int_as_float(p0.y), acc);
        acc = fmaf(h1, __int_as_float(p1.y), acc);
    }
    if (i < end) {
        int2 p0 = epair[i];
        acc = fmaf(u2[(size_t)p0.x * 16 + j], __int_as_float(p0.y), acc);
    }
    float v = (j < 10) ? (acc + b[j]) : -1e30f;
    float m = v;
#pragma unroll
    for (int o = 8; o; o >>= 1) m = fmaxf(m, __shfl_xor(m, o, 64));
    float p = (j < 10) ? __expf(v - m) : 0.f;
    float s2 = p;
#pragma unroll
    for (int o = 8; o; o >>= 1) s2 += __shfl_xor(s2, o, 64);
    if (j < 10) out[(size_t)n * 10 + j] = p / s2;
}

extern "C" void kernel_launch(void* const* d_in, const int* in_sizes, int n_in,
                              void* d_out, int out_size, void* d_ws, size_t ws_size,
                              hipStream_t stream) {
    const float* x  = (const float*)d_in[0];
    const int*   ei = (const int*)d_in[1];
    const float* ew = (const float*)d_in[2];
    const float* W0 = (const float*)d_in[3];
    const float* b0 = (const float*)d_in[4];
    const float* W1 = (const float*)d_in[5];
    const float* b1 = (const float*)d_in[6];
    const float* W2 = (const float*)d_in[7];
    const float* b2 = (const float*)d_in[8];
    float* out = (float*)d_out;

    const int* src = ei;
    const int* dst = ei + NE;

    char* ws = (char*)d_ws;
    const size_t SZ = (size_t)NN * 64 * sizeof(float);        // 12.8 MB
    float* C      = (float*)ws;                               // h1
    float* D      = (float*)(ws + SZ);                        // h2
    float* U      = (float*)(ws + 2 * SZ);                    // u2 (padded 16), 3.2 MB
    int2*  epair  = (int2*)(ws + 2 * SZ + (size_t)NN * 16 * 4);   // 6.4 MB
    char*  tail   = ws + 2 * SZ + (size_t)NN * 16 * 4 + (size_t)NE * 8;
    int*   offs   = (int*)tail;                               // (NN+1)*4
    int*   cursor = offs + (NN + 1);                          // NN*4
    int*   bsum   = cursor + NN;                              // 32*4
    int*   bscan  = bsum + 32;                                // 32*4

    const int gE   = (NE + 255) / 256;         // 3125
    const int gN   = (NN + 255) / 256;         // 196
    const int gN64 = (NN * 64 + 255) / 256;    // 12500
    const int gN16 = (NN * 16 + 255) / 256;    // 3125

    // ----- CSR build -----
    hipMemsetAsync(cursor, 0, (size_t)NN * sizeof(int), stream);
    count_kernel<<<gE, 256, 0, stream>>>(dst, cursor);
    scan1_kernel<<<25, 256, 0, stream>>>(cursor, offs, bsum);
    scan2_kernel<<<1, 64, 0, stream>>>(bsum, bscan);
    scan3_kernel<<<gN, 256, 0, stream>>>(offs, bscan, cursor);
    scatter_kernel<<<gE, 256, 0, stream>>>(src, dst, ew, cursor, epair);

    // ----- layer 0: h1 = softmax(agg(x)@W0 + b0) -----
    fusedA_kernel<<<gN64, 256, 0, stream>>>(x, offs, epair, W0, b0, C);

    // ----- layer 1: h2 = softmax(agg(h1)@W1 + b1) -----
    fusedA_kernel<<<gN64, 256, 0, stream>>>(C, offs, epair, W1, b1, D);

    // ----- layer 2 linear: u2 = h2 @ W2 (64->10, pad 16) -----
    lin16_kernel<<<gN16, 256, 0, stream>>>(D, W2, U);

    // ----- layer 2: out = softmax(agg(u2) + b2) -----
    aggsm10_kernel<<<gN16, 256, 0, stream>>>(U, offs, epair, b2, out);
}

// Round 10
// 312.151 us; speedup vs baseline: 1.9564x; 1.0217x over previous
//
#include <hip/hip_runtime.h>
#include <hip/hip_fp16.h>

#define NN 50000
#define NE 800000

// ============ cast x (fp32) -> x16 (fp16), vectorized ============
__global__ __launch_bounds__(256) void cast16_kernel(const float* __restrict__ x,
                                                     __half* __restrict__ x16) {
    int i = blockIdx.x * 256 + threadIdx.x;  // over NN*64/2 half2 elements
    if (i < NN * 32) {
        float2 v = reinterpret_cast<const float2*>(x)[i];
        reinterpret_cast<__half2*>(x16)[i] = __floats2half2_rn(v.x, v.y);
    }
}

// ============ CSR build ============
__global__ __launch_bounds__(256) void count_kernel(const int* __restrict__ dst,
                                                    int* __restrict__ cursor) {
    int e = blockIdx.x * 256 + threadIdx.x;
    if (e < NE) atomicAdd(&cursor[dst[e]], 1);
}

// phase 1: 25 blocks x 256 thr, each block scans 2048 counts
__global__ __launch_bounds__(256) void scan1_kernel(const int* __restrict__ cnt,
                                                    int* __restrict__ offs,
                                                    int* __restrict__ bsum) {
    __shared__ int sm[256];
    int b = blockIdx.x, t = threadIdx.x;
    int base = b * 2048 + t * 8;
    int v[8];
    int s = 0;
#pragma unroll
    for (int i = 0; i < 8; ++i) {
        int idx = base + i;
        int c = (idx < NN) ? cnt[idx] : 0;
        v[i] = s;
        s += c;
    }
    sm[t] = s;
    __syncthreads();
    for (int off = 1; off < 256; off <<= 1) {
        int y = (t >= off) ? sm[t - off] : 0;
        __syncthreads();
        sm[t] += y;
        __syncthreads();
    }
    int excl = sm[t] - s;
#pragma unroll
    for (int i = 0; i < 8; ++i) {
        int idx = base + i;
        if (idx < NN) offs[idx] = excl + v[i];
    }
    if (t == 255) bsum[b] = sm[255];
}

// phase 2+3 merged: each block re-scans the 25 block sums (cheap), applies
// offset, inits cursor, writes offs[NN]
__global__ __launch_bounds__(256) void scan3_kernel(int* __restrict__ offs,
                                                    const int* __restrict__ bsum,
                                                    int* __restrict__ cursor) {
    __shared__ int sb[32];
    if (threadIdx.x == 0) {
        int run = 0;
        for (int k = 0; k < 25; ++k) {
            sb[k] = run;
            run += bsum[k];
        }
    }
    __syncthreads();
    int i = blockIdx.x * 256 + threadIdx.x;
    if (i < NN) {
        int v = offs[i] + sb[i >> 11];
        offs[i] = v;
        cursor[i] = v;
    }
    if (i == 0) offs[NN] = NE;
}

__global__ __launch_bounds__(256) void scatter_kernel(const int* __restrict__ src,
                                                      const int* __restrict__ dst,
                                                      const float* __restrict__ ew,
                                                      int* __restrict__ cursor,
                                                      int2* __restrict__ epair) {
    int e = blockIdx.x * 256 + threadIdx.x;
    if (e >= NE) return;
    int d = dst[e];
    int pos = atomicAdd(&cursor[d], 1);
    epair[pos] = make_int2(src[e], __float_as_int(ew[e]));
}

// ============ fused 64-dim layer (fp16 gather): out16 = softmax(agg(h16)@W + b) ============
__global__ __launch_bounds__(256) void fusedAh_kernel(const __half* __restrict__ h,
                                                      const int* __restrict__ offs,
                                                      const int2* __restrict__ epair,
                                                      const float* __restrict__ W,
                                                      const float* __restrict__ b,
                                                      __half* __restrict__ out) {
    __shared__ float Wl[4096];  // 16 KB
    int tid = threadIdx.x;
    for (int i = tid; i < 1024; i += 256)
        reinterpret_cast<float4*>(Wl)[i] = reinterpret_cast<const float4*>(W)[i];
    __syncthreads();

    int g = blockIdx.x * 256 + tid;
    int n = g >> 6, lane = g & 63;
    if (n >= NN) return;
    int beg = offs[n], end = offs[n + 1];
    float acc = 0.f;
    int i = beg;
    for (; i + 3 < end; i += 4) {
        int2 p0 = epair[i], p1 = epair[i + 1], p2 = epair[i + 2], p3 = epair[i + 3];
        float h0 = __half2float(h[(size_t)p0.x * 64 + lane]);
        float h1 = __half2float(h[(size_t)p1.x * 64 + lane]);
        float h2 = __half2float(h[(size_t)p2.x * 64 + lane]);
        float h3 = __half2float(h[(size_t)p3.x * 64 + lane]);
        acc = fmaf(h0, __int_as_float(p0.y), acc);
        acc = fmaf(h1, __int_as_float(p1.y), acc);
        acc = fmaf(h2, __int_as_float(p2.y), acc);
        acc = fmaf(h3, __int_as_float(p3.y), acc);
    }
    for (; i < end; ++i) {
        int2 p0 = epair[i];
        acc = fmaf(__half2float(h[(size_t)p0.x * 64 + lane]), __int_as_float(p0.y), acc);
    }

    // matvec via readlane broadcast (VALU/SGPR, no LDS for the broadcast)
    int ai = __float_as_int(acc);
    float y0 = 0.f, y1 = 0.f, y2 = 0.f, y3 = 0.f;
#pragma unroll
    for (int k = 0; k < 64; k += 4) {
        float a0 = __int_as_float(__builtin_amdgcn_readlane(ai, k));
        float a1 = __int_as_float(__builtin_amdgcn_readlane(ai, k + 1));
        float a2 = __int_as_float(__builtin_amdgcn_readlane(ai, k + 2));
        float a3 = __int_as_float(__builtin_amdgcn_readlane(ai, k + 3));
        y0 = fmaf(a0, Wl[(k + 0) * 64 + lane], y0);
        y1 = fmaf(a1, Wl[(k + 1) * 64 + lane], y1);
        y2 = fmaf(a2, Wl[(k + 2) * 64 + lane], y2);
        y3 = fmaf(a3, Wl[(k + 3) * 64 + lane], y3);
    }
    float y = (y0 + y1) + (y2 + y3) + b[lane];

    // softmax over 64
    float m = y;
#pragma unroll
    for (int o = 32; o; o >>= 1) m = fmaxf(m, __shfl_xor(m, o, 64));
    float p = __expf(y - m);
    float s2 = p;
#pragma unroll
    for (int o = 32; o; o >>= 1) s2 += __shfl_xor(s2, o, 64);
    out[(size_t)n * 64 + lane] = __float2half_rn(p / s2);
}

// ============ linear 64 -> 10 (fp16 in, fp16 out, padded stride 16) ============
__global__ __launch_bounds__(256) void lin16h_kernel(const __half* __restrict__ H,
                                                     const float* __restrict__ W2,
                                                     __half* __restrict__ out) {
    int g = blockIdx.x * 256 + threadIdx.x;
    int n = g >> 4, j = g & 15;
    if (n >= NN) return;
    float acc = 0.f;
    if (j < 10) {
        const __half* hrow = H + (size_t)n * 64;
#pragma unroll
        for (int k = 0; k < 64; ++k) acc += __half2float(hrow[k]) * W2[k * 10 + j];
    }
    out[(size_t)n * 16 + j] = __float2half_rn(acc);
}

// ============ final: out = softmax(agg(u2) + b2), 10 classes; u2 fp16 (L2-resident) ============
__global__ __launch_bounds__(256) void aggsm10h_kernel(const __half* __restrict__ u2,
                                                       const int* __restrict__ offs,
                                                       const int2* __restrict__ epair,
                                                       const float* __restrict__ b,
                                                       float* __restrict__ out) {
    int g = blockIdx.x * 256 + threadIdx.x;
    int n = g >> 4, j = g & 15;
    if (n >= NN) return;
    int beg = offs[n], end = offs[n + 1];
    float acc = 0.f;
    int i = beg;
    for (; i + 1 < end; i += 2) {
        int2 p0 = epair[i];
        int2 p1 = epair[i + 1];
        float h0 = __half2float(u2[(size_t)p0.x * 16 + j]);
        float h1 = __half2float(u2[(size_t)p1.x * 16 + j]);
        acc = fmaf(h0, __int_as_float(p0.y), acc);
        acc = fmaf(h1, __int_as_float(p1.y), acc);
    }
    if (i < end) {
        int2 p0 = epair[i];
        acc = fmaf(__half2float(u2[(size_t)p0.x * 16 + j]), __int_as_float(p0.y), acc);
    }
    float v = (j < 10) ? (acc + b[j]) : -1e30f;
    float m = v;
#pragma unroll
    for (int o = 8; o; o >>= 1) m = fmaxf(m, __shfl_xor(m, o, 64));
    float p = (j < 10) ? __expf(v - m) : 0.f;
    float s2 = p;
#pragma unroll
    for (int o = 8; o; o >>= 1) s2 += __shfl_xor(s2, o, 64);
    if (j < 10) out[(size_t)n * 10 + j] = p / s2;
}

extern "C" void kernel_launch(void* const* d_in, const int* in_sizes, int n_in,
                              void* d_out, int out_size, void* d_ws, size_t ws_size,
                              hipStream_t stream) {
    const float* x  = (const float*)d_in[0];
    const int*   ei = (const int*)d_in[1];
    const float* ew = (const float*)d_in[2];
    const float* W0 = (const float*)d_in[3];
    const float* b0 = (const float*)d_in[4];
    const float* W1 = (const float*)d_in[5];
    const float* b1 = (const float*)d_in[6];
    const float* W2 = (const float*)d_in[7];
    const float* b2 = (const float*)d_in[8];
    float* out = (float*)d_out;

    const int* src = ei;
    const int* dst = ei + NE;

    // workspace layout (fp16 feature buffers)
    char* ws = (char*)d_ws;
    const size_t SZH = (size_t)NN * 64 * sizeof(__half);      // 6.4 MB
    __half* X16  = (__half*)ws;                               // 6.4 MB
    __half* H1   = (__half*)(ws + SZH);                       // 6.4 MB
    __half* H2   = (__half*)(ws + 2 * SZH);                   // 6.4 MB
    __half* U    = (__half*)(ws + 3 * SZH);                   // NN*16*2 = 1.6 MB
    int2*  epair = (int2*)(ws + 3 * SZH + (size_t)NN * 16 * 2);   // 6.4 MB
    char*  tail  = ws + 3 * SZH + (size_t)NN * 16 * 2 + (size_t)NE * 8;
    int*   offs   = (int*)tail;                               // (NN+1)*4
    int*   cursor = offs + (NN + 1);                          // NN*4
    int*   bsum   = cursor + NN;                              // 32*4

    const int gE   = (NE + 255) / 256;         // 3125
    const int gN   = (NN + 255) / 256;         // 196
    const int gC   = (NN * 32 + 255) / 256;    // 6250
    const int gN64 = (NN * 64 + 255) / 256;    // 12500
    const int gN16 = (NN * 16 + 255) / 256;    // 3125

    // ----- CSR build + x cast -----
    hipMemsetAsync(cursor, 0, (size_t)NN * sizeof(int), stream);
    cast16_kernel<<<gC, 256, 0, stream>>>(x, X16);
    count_kernel<<<gE, 256, 0, stream>>>(dst, cursor);
    scan1_kernel<<<25, 256, 0, stream>>>(cursor, offs, bsum);
    scan3_kernel<<<gN, 256, 0, stream>>>(offs, bsum, cursor);
    scatter_kernel<<<gE, 256, 0, stream>>>(src, dst, ew, cursor, epair);

    // ----- layer 0: h1 = softmax(agg(x)@W0 + b0) -----
    fusedAh_kernel<<<gN64, 256, 0, stream>>>(X16, offs, epair, W0, b0, H1);

    // ----- layer 1: h2 = softmax(agg(h1)@W1 + b1) -----
    fusedAh_kernel<<<gN64, 256, 0, stream>>>(H1, offs, epair, W1, b1, H2);

    // ----- layer 2 linear: u2 = h2 @ W2 (64->10, pad 16) -----
    lin16h_kernel<<<gN16, 256, 0, stream>>>(H2, W2, U);

    // ----- layer 2: out = softmax(agg(u2) + b2) -----
    aggsm10h_kernel<<<gN16, 256, 0, stream>>>(U, offs, epair, b2, out);
}

// Round 12
// 294.085 us; speedup vs baseline: 2.0766x; 1.0614x over previous
//
#include <hip/hip_runtime.h>
#include <hip/hip_fp16.h>

#define NN 50000
#define NE 800000

// ============ cast x (fp32) -> x16 (fp16), vectorized ============
__global__ __launch_bounds__(256) void cast16_kernel(const float* __restrict__ x,
                                                     __half* __restrict__ x16) {
    int i = blockIdx.x * 256 + threadIdx.x;  // over NN*64/2 half2 elements
    if (i < NN * 32) {
        float2 v = reinterpret_cast<const float2*>(x)[i];
        reinterpret_cast<__half2*>(x16)[i] = __floats2half2_rn(v.x, v.y);
    }
}

// ============ CSR build ============
__global__ __launch_bounds__(256) void count_kernel(const int* __restrict__ dst,
                                                    int* __restrict__ cursor) {
    int e = blockIdx.x * 256 + threadIdx.x;
    if (e < NE) atomicAdd(&cursor[dst[e]], 1);
}

__global__ __launch_bounds__(256) void scan1_kernel(const int* __restrict__ cnt,
                                                    int* __restrict__ offs,
                                                    int* __restrict__ bsum) {
    __shared__ int sm[256];
    int b = blockIdx.x, t = threadIdx.x;
    int base = b * 2048 + t * 8;
    int v[8];
    int s = 0;
#pragma unroll
    for (int i = 0; i < 8; ++i) {
        int idx = base + i;
        int c = (idx < NN) ? cnt[idx] : 0;
        v[i] = s;
        s += c;
    }
    sm[t] = s;
    __syncthreads();
    for (int off = 1; off < 256; off <<= 1) {
        int y = (t >= off) ? sm[t - off] : 0;
        __syncthreads();
        sm[t] += y;
        __syncthreads();
    }
    int excl = sm[t] - s;
#pragma unroll
    for (int i = 0; i < 8; ++i) {
        int idx = base + i;
        if (idx < NN) offs[idx] = excl + v[i];
    }
    if (t == 255) bsum[b] = sm[255];
}

// phase 2+3 merged
__global__ __launch_bounds__(256) void scan3_kernel(int* __restrict__ offs,
                                                    const int* __restrict__ bsum,
                                                    int* __restrict__ cursor) {
    __shared__ int sb[32];
    if (threadIdx.x == 0) {
        int run = 0;
        for (int k = 0; k < 25; ++k) {
            sb[k] = run;
            run += bsum[k];
        }
    }
    __syncthreads();
    int i = blockIdx.x * 256 + threadIdx.x;
    if (i < NN) {
        int v = offs[i] + sb[i >> 11];
        offs[i] = v;
        cursor[i] = v;
    }
    if (i == 0) offs[NN] = NE;
}

__global__ __launch_bounds__(256) void scatter_kernel(const int* __restrict__ src,
                                                      const int* __restrict__ dst,
                                                      const float* __restrict__ ew,
                                                      int* __restrict__ cursor,
                                                      int2* __restrict__ epair) {
    int e = blockIdx.x * 256 + threadIdx.x;
    if (e >= NE) return;
    int d = dst[e];
    int pos = atomicAdd(&cursor[d], 1);
    epair[pos] = make_int2(src[e], __float_as_int(ew[e]));
}

// ============ fused 64-dim layer, 4 nodes per wave ============
// out16 = softmax(agg(h16)@W + b). Gather per node (full-wave, lane=feature),
// then ONE matvec loop shares each Wl ds_read across 4 nodes via readlane.
__global__ __launch_bounds__(256) void fused4_kernel(const __half* __restrict__ h,
                                                     const int* __restrict__ offs,
                                                     const int2* __restrict__ epair,
                                                     const float* __restrict__ W,
                                                     const float* __restrict__ b,
                                                     __half* __restrict__ out) {
    __shared__ float Wl[4096];  // 16 KB
    int tid = threadIdx.x;
    for (int i = tid; i < 1024; i += 256)
        reinterpret_cast<float4*>(Wl)[i] = reinterpret_cast<const float4*>(W)[i];
    __syncthreads();

    int lane = tid & 63;
    int wid = (blockIdx.x * 256 + tid) >> 6;  // global wave id
    int n0 = wid * 4;
    if (n0 >= NN) return;

    float a0 = 0.f, a1 = 0.f, a2 = 0.f, a3 = 0.f;
#pragma unroll
    for (int m = 0; m < 4; ++m) {
        int n = n0 + m;
        int beg = offs[n], end = offs[n + 1];
        float a = 0.f;
        int i = beg;
        for (; i + 3 < end; i += 4) {
            int2 p0 = epair[i], p1 = epair[i + 1], p2 = epair[i + 2], p3 = epair[i + 3];
            float h0 = __half2float(h[(size_t)p0.x * 64 + lane]);
            float h1 = __half2float(h[(size_t)p1.x * 64 + lane]);
            float h2 = __half2float(h[(size_t)p2.x * 64 + lane]);
            float h3 = __half2float(h[(size_t)p3.x * 64 + lane]);
            a = fmaf(h0, __int_as_float(p0.y), a);
            a = fmaf(h1, __int_as_float(p1.y), a);
            a = fmaf(h2, __int_as_float(p2.y), a);
            a = fmaf(h3, __int_as_float(p3.y), a);
        }
        for (; i < end; ++i) {
            int2 p0 = epair[i];
            a = fmaf(__half2float(h[(size_t)p0.x * 64 + lane]), __int_as_float(p0.y), a);
        }
        if (m == 0) a0 = a;
        else if (m == 1) a1 = a;
        else if (m == 2) a2 = a;
        else a3 = a;
    }

    // shared matvec: per k one ds_read serves 4 nodes (readlane broadcast, VALU)
    int i0 = __float_as_int(a0), i1 = __float_as_int(a1);
    int i2 = __float_as_int(a2), i3 = __float_as_int(a3);
    float y0 = 0.f, y1 = 0.f, y2 = 0.f, y3 = 0.f;
#pragma unroll
    for (int k = 0; k < 64; ++k) {
        float w = Wl[k * 64 + lane];
        y0 = fmaf(__int_as_float(__builtin_amdgcn_readlane(i0, k)), w, y0);
        y1 = fmaf(__int_as_float(__builtin_amdgcn_readlane(i1, k)), w, y1);
        y2 = fmaf(__int_as_float(__builtin_amdgcn_readlane(i2, k)), w, y2);
        y3 = fmaf(__int_as_float(__builtin_amdgcn_readlane(i3, k)), w, y3);
    }
    float bl = b[lane];
    y0 += bl; y1 += bl; y2 += bl; y3 += bl;

    // softmax over 64 lanes, 4 nodes sequentially
#pragma unroll
    for (int m = 0; m < 4; ++m) {
        float y = (m == 0) ? y0 : (m == 1) ? y1 : (m == 2) ? y2 : y3;
        float mx = y;
#pragma unroll
        for (int o = 32; o; o >>= 1) mx = fmaxf(mx, __shfl_xor(mx, o, 64));
        float p = __expf(y - mx);
        float s2 = p;
#pragma unroll
        for (int o = 32; o; o >>= 1) s2 += __shfl_xor(s2, o, 64);
        out[(size_t)(n0 + m) * 64 + lane] = __float2half_rn(p / s2);
    }
}

// ============ linear 64 -> 10 (fp16 in, fp16 out, padded stride 16) ============
__global__ __launch_bounds__(256) void lin16h_kernel(const __half* __restrict__ H,
                                                     const float* __restrict__ W2,
                                                     __half* __restrict__ out) {
    int g = blockIdx.x * 256 + threadIdx.x;
    int n = g >> 4, j = g & 15;
    if (n >= NN) return;
    float acc = 0.f;
    if (j < 10) {
        const __half* hrow = H + (size_t)n * 64;
#pragma unroll
        for (int k = 0; k < 64; ++k) acc += __half2float(hrow[k]) * W2[k * 10 + j];
    }
    out[(size_t)n * 16 + j] = __float2half_rn(acc);
}

// ============ final: out = softmax(agg(u2) + b2), 10 classes ============
__global__ __launch_bounds__(256) void aggsm10h_kernel(const __half* __restrict__ u2,
                                                       const int* __restrict__ offs,
                                                       const int2* __restrict__ epair,
                                                       const float* __restrict__ b,
                                                       float* __restrict__ out) {
    int g = blockIdx.x * 256 + threadIdx.x;
    int n = g >> 4, j = g & 15;
    if (n >= NN) return;
    int beg = offs[n], end = offs[n + 1];
    float acc = 0.f;
    int i = beg;
    for (; i + 1 < end; i += 2) {
        int2 p0 = epair[i];
        int2 p1 = epair[i + 1];
        float h0 = __half2float(u2[(size_t)p0.x * 16 + j]);
        float h1 = __half2float(u2[(size_t)p1.x * 16 + j]);
        acc = fmaf(h0, __int_as_float(p0.y), acc);
        acc = fmaf(h1, __int_as_float(p1.y), acc);
    }
    if (i < end) {
        int2 p0 = epair[i];
        acc = fmaf(__half2float(u2[(size_t)p0.x * 16 + j]), __int_as_float(p0.y), acc);
    }
    float v = (j < 10) ? (acc + b[j]) : -1e30f;
    float m = v;
#pragma unroll
    for (int o = 8; o; o >>= 1) m = fmaxf(m, __shfl_xor(m, o, 64));
    float p = (j < 10) ? __expf(v - m) : 0.f;
    float s2 = p;
#pragma unroll
    for (int o = 8; o; o >>= 1) s2 += __shfl_xor(s2, o, 64);
    if (j < 10) out[(size_t)n * 10 + j] = p / s2;
}

extern "C" void kernel_launch(void* const* d_in, const int* in_sizes, int n_in,
                              void* d_out, int out_size, void* d_ws, size_t ws_size,
                              hipStream_t stream) {
    const float* x  = (const float*)d_in[0];
    const int*   ei = (const int*)d_in[1];
    const float* ew = (const float*)d_in[2];
    const float* W0 = (const float*)d_in[3];
    const float* b0 = (const float*)d_in[4];
    const float* W1 = (const float*)d_in[5];
    const float* b1 = (const float*)d_in[6];
    const float* W2 = (const float*)d_in[7];
    const float* b2 = (const float*)d_in[8];
    float* out = (float*)d_out;

    const int* src = ei;
    const int* dst = ei + NE;

    char* ws = (char*)d_ws;
    const size_t SZH = (size_t)NN * 64 * sizeof(__half);      // 6.4 MB
    __half* X16  = (__half*)ws;
    __half* H1   = (__half*)(ws + SZH);
    __half* H2   = (__half*)(ws + 2 * SZH);
    __half* U    = (__half*)(ws + 3 * SZH);                   // NN*16*2 = 1.6 MB
    int2*  epair = (int2*)(ws + 3 * SZH + (size_t)NN * 16 * 2);
    char*  tail  = ws + 3 * SZH + (size_t)NN * 16 * 2 + (size_t)NE * 8;
    int*   offs   = (int*)tail;
    int*   cursor = offs + (NN + 1);
    int*   bsum   = cursor + NN;

    const int gE   = (NE + 255) / 256;          // 3125
    const int gN   = (NN + 255) / 256;          // 196
    const int gC   = (NN * 32 + 255) / 256;     // 6250
    const int gF4  = (NN * 16 + 255) / 256;     // 3125 blocks: 4 waves x 4 nodes
    const int gN16 = (NN * 16 + 255) / 256;     // 3125

    // ----- CSR build + x cast -----
    hipMemsetAsync(cursor, 0, (size_t)NN * sizeof(int), stream);
    cast16_kernel<<<gC, 256, 0, stream>>>(x, X16);
    count_kernel<<<gE, 256, 0, stream>>>(dst, cursor);
    scan1_kernel<<<25, 256, 0, stream>>>(cursor, offs, bsum);
    scan3_kernel<<<gN, 256, 0, stream>>>(offs, bsum, cursor);
    scatter_kernel<<<gE, 256, 0, stream>>>(src, dst, ew, cursor, epair);

    // ----- layer 0: h1 = softmax(agg(x)@W0 + b0) -----
    fused4_kernel<<<gF4, 256, 0, stream>>>(X16, offs, epair, W0, b0, H1);

    // ----- layer 1: h2 = softmax(agg(h1)@W1 + b1) -----
    fused4_kernel<<<gF4, 256, 0, stream>>>(H1, offs, epair, W1, b1, H2);

    // ----- layer 2 linear: u2 = h2 @ W2 (64->10, pad 16) -----
    lin16h_kernel<<<gN16, 256, 0, stream>>>(H2, W2, U);

    // ----- layer 2: out = softmax(agg(u2) + b2) -----
    aggsm10h_kernel<<<gN16, 256, 0, stream>>>(U, offs, epair, b2, out);
}

// Round 13
// 279.349 us; speedup vs baseline: 2.1861x; 1.0528x over previous
//
#include <hip/hip_runtime.h>
#include <hip/hip_fp16.h>

#define NN 50000
#define NE 800000

// ============ cast x (fp32) -> x16 (fp16), vectorized ============
__global__ __launch_bounds__(256) void cast16_kernel(const float* __restrict__ x,
                                                     __half* __restrict__ x16) {
    int i = blockIdx.x * 256 + threadIdx.x;
    if (i < NN * 32) {
        float2 v = reinterpret_cast<const float2*>(x)[i];
        reinterpret_cast<__half2*>(x16)[i] = __floats2half2_rn(v.x, v.y);
    }
}

// ============ CSR build ============
__global__ __launch_bounds__(256) void count_kernel(const int* __restrict__ dst,
                                                    int* __restrict__ cursor) {
    int e = blockIdx.x * 256 + threadIdx.x;
    if (e < NE) atomicAdd(&cursor[dst[e]], 1);
}

__global__ __launch_bounds__(256) void scan1_kernel(const int* __restrict__ cnt,
                                                    int* __restrict__ offs,
                                                    int* __restrict__ bsum) {
    __shared__ int sm[256];
    int b = blockIdx.x, t = threadIdx.x;
    int base = b * 2048 + t * 8;
    int v[8];
    int s = 0;
#pragma unroll
    for (int i = 0; i < 8; ++i) {
        int idx = base + i;
        int c = (idx < NN) ? cnt[idx] : 0;
        v[i] = s;
        s += c;
    }
    sm[t] = s;
    __syncthreads();
    for (int off = 1; off < 256; off <<= 1) {
        int y = (t >= off) ? sm[t - off] : 0;
        __syncthreads();
        sm[t] += y;
        __syncthreads();
    }
    int excl = sm[t] - s;
#pragma unroll
    for (int i = 0; i < 8; ++i) {
        int idx = base + i;
        if (idx < NN) offs[idx] = excl + v[i];
    }
    if (t == 255) bsum[b] = sm[255];
}

// phase 2+3 merged
__global__ __launch_bounds__(256) void scan3_kernel(int* __restrict__ offs,
                                                    const int* __restrict__ bsum,
                                                    int* __restrict__ cursor) {
    __shared__ int sb[32];
    if (threadIdx.x == 0) {
        int run = 0;
        for (int k = 0; k < 25; ++k) {
            sb[k] = run;
            run += bsum[k];
        }
    }
    __syncthreads();
    int i = blockIdx.x * 256 + threadIdx.x;
    if (i < NN) {
        int v = offs[i] + sb[i >> 11];
        offs[i] = v;
        cursor[i] = v;
    }
    if (i == 0) offs[NN] = NE;
}

__global__ __launch_bounds__(256) void scatter_kernel(const int* __restrict__ src,
                                                      const int* __restrict__ dst,
                                                      const float* __restrict__ ew,
                                                      int* __restrict__ cursor,
                                                      int2* __restrict__ epair) {
    int e = blockIdx.x * 256 + threadIdx.x;
    if (e >= NE) return;
    int d = dst[e];
    int pos = atomicAdd(&cursor[d], 1);
    epair[pos] = make_int2(src[e], __float_as_int(ew[e]));
}

// ============ fused 64-dim layer, 4 nodes per wave, scalar-pipe gather ============
// out16 = softmax(agg(h16)@W + b). All per-edge metadata is wave-uniform:
// readfirstlane forces it to SGPR/SALU/s_load, leaving only {ushort load, cvt, fma}
// on the vector pipes per edge.
__global__ __launch_bounds__(256) void fused4_kernel(const __half* __restrict__ h,
                                                     const int* __restrict__ offs,
                                                     const int2* __restrict__ epair,
                                                     const float* __restrict__ W,
                                                     const float* __restrict__ b,
                                                     __half* __restrict__ out) {
    __shared__ float Wl[4096];  // 16 KB
    int tid = threadIdx.x;
    for (int i = tid; i < 1024; i += 256)
        reinterpret_cast<float4*>(Wl)[i] = reinterpret_cast<const float4*>(W)[i];
    __syncthreads();

    int lane = tid & 63;
    int wid = (blockIdx.x * 256 + tid) >> 6;
    int n0 = wid * 4;
    if (n0 >= NN) return;

    float av[4];
#pragma unroll
    for (int m = 0; m < 4; ++m) {
        int n = n0 + m;
        int beg = __builtin_amdgcn_readfirstlane(offs[n]);
        int end = __builtin_amdgcn_readfirstlane(offs[n + 1]);
        float a = 0.f;
        int i = beg;
        for (; i + 7 < end; i += 8) {
            // uniform epair reads -> scalar cache; 8 gathers in flight
            int2 q0 = epair[i + 0], q1 = epair[i + 1], q2 = epair[i + 2], q3 = epair[i + 3];
            int2 q4 = epair[i + 4], q5 = epair[i + 5], q6 = epair[i + 6], q7 = epair[i + 7];
            int s0 = __builtin_amdgcn_readfirstlane(q0.x);
            int s1 = __builtin_amdgcn_readfirstlane(q1.x);
            int s2 = __builtin_amdgcn_readfirstlane(q2.x);
            int s3 = __builtin_amdgcn_readfirstlane(q3.x);
            int s4 = __builtin_amdgcn_readfirstlane(q4.x);
            int s5 = __builtin_amdgcn_readfirstlane(q5.x);
            int s6 = __builtin_amdgcn_readfirstlane(q6.x);
            int s7 = __builtin_amdgcn_readfirstlane(q7.x);
            float h0 = __half2float(h[((size_t)s0 << 6) + lane]);
            float h1 = __half2float(h[((size_t)s1 << 6) + lane]);
            float h2 = __half2float(h[((size_t)s2 << 6) + lane]);
            float h3 = __half2float(h[((size_t)s3 << 6) + lane]);
            float h4 = __half2float(h[((size_t)s4 << 6) + lane]);
            float h5 = __half2float(h[((size_t)s5 << 6) + lane]);
            float h6 = __half2float(h[((size_t)s6 << 6) + lane]);
            float h7 = __half2float(h[((size_t)s7 << 6) + lane]);
            a = fmaf(h0, __int_as_float(__builtin_amdgcn_readfirstlane(q0.y)), a);
            a = fmaf(h1, __int_as_float(__builtin_amdgcn_readfirstlane(q1.y)), a);
            a = fmaf(h2, __int_as_float(__builtin_amdgcn_readfirstlane(q2.y)), a);
            a = fmaf(h3, __int_as_float(__builtin_amdgcn_readfirstlane(q3.y)), a);
            a = fmaf(h4, __int_as_float(__builtin_amdgcn_readfirstlane(q4.y)), a);
            a = fmaf(h5, __int_as_float(__builtin_amdgcn_readfirstlane(q5.y)), a);
            a = fmaf(h6, __int_as_float(__builtin_amdgcn_readfirstlane(q6.y)), a);
            a = fmaf(h7, __int_as_float(__builtin_amdgcn_readfirstlane(q7.y)), a);
        }
        for (; i < end; ++i) {
            int2 q = epair[i];
            int s = __builtin_amdgcn_readfirstlane(q.x);
            float w = __int_as_float(__builtin_amdgcn_readfirstlane(q.y));
            a = fmaf(__half2float(h[((size_t)s << 6) + lane]), w, a);
        }
        av[m] = a;
    }

    // shared matvec: per k one ds_read serves 4 nodes (readlane broadcast)
    int i0 = __float_as_int(av[0]), i1 = __float_as_int(av[1]);
    int i2 = __float_as_int(av[2]), i3 = __float_as_int(av[3]);
    float y0 = 0.f, y1 = 0.f, y2 = 0.f, y3 = 0.f;
#pragma unroll
    for (int k = 0; k < 64; ++k) {
        float w = Wl[k * 64 + lane];
        y0 = fmaf(__int_as_float(__builtin_amdgcn_readlane(i0, k)), w, y0);
        y1 = fmaf(__int_as_float(__builtin_amdgcn_readlane(i1, k)), w, y1);
        y2 = fmaf(__int_as_float(__builtin_amdgcn_readlane(i2, k)), w, y2);
        y3 = fmaf(__int_as_float(__builtin_amdgcn_readlane(i3, k)), w, y3);
    }
    float bl = b[lane];
    y0 += bl; y1 += bl; y2 += bl; y3 += bl;

    // softmax over 64 lanes, 4 nodes sequentially
#pragma unroll
    for (int m = 0; m < 4; ++m) {
        float y = (m == 0) ? y0 : (m == 1) ? y1 : (m == 2) ? y2 : y3;
        float mx = y;
#pragma unroll
        for (int o = 32; o; o >>= 1) mx = fmaxf(mx, __shfl_xor(mx, o, 64));
        float p = __expf(y - mx);
        float s2 = p;
#pragma unroll
        for (int o = 32; o; o >>= 1) s2 += __shfl_xor(s2, o, 64);
        out[(size_t)(n0 + m) * 64 + lane] = __float2half_rn(p / s2);
    }
}

// ============ linear 64 -> 10 (fp16 in, fp16 out, padded stride 16) ============
__global__ __launch_bounds__(256) void lin16h_kernel(const __half* __restrict__ H,
                                                     const float* __restrict__ W2,
                                                     __half* __restrict__ out) {
    int g = blockIdx.x * 256 + threadIdx.x;
    int n = g >> 4, j = g & 15;
    if (n >= NN) return;
    float acc = 0.f;
    if (j < 10) {
        const __half* hrow = H + (size_t)n * 64;
#pragma unroll
        for (int k = 0; k < 64; ++k) acc += __half2float(hrow[k]) * W2[k * 10 + j];
    }
    out[(size_t)n * 16 + j] = __float2half_rn(acc);
}

// ============ final: out = softmax(agg(u2) + b2), 10 classes ============
__global__ __launch_bounds__(256) void aggsm10h_kernel(const __half* __restrict__ u2,
                                                       const int* __restrict__ offs,
                                                       const int2* __restrict__ epair,
                                                       const float* __restrict__ b,
                                                       float* __restrict__ out) {
    int g = blockIdx.x * 256 + threadIdx.x;
    int n = g >> 4, j = g & 15;
    if (n >= NN) return;
    int beg = offs[n], end = offs[n + 1];
    float acc = 0.f;
    int i = beg;
    for (; i + 3 < end; i += 4) {
        int2 p0 = epair[i], p1 = epair[i + 1], p2 = epair[i + 2], p3 = epair[i + 3];
        float h0 = __half2float(u2[(size_t)p0.x * 16 + j]);
        float h1 = __half2float(u2[(size_t)p1.x * 16 + j]);
        float h2 = __half2float(u2[(size_t)p2.x * 16 + j]);
        float h3 = __half2float(u2[(size_t)p3.x * 16 + j]);
        acc = fmaf(h0, __int_as_float(p0.y), acc);
        acc = fmaf(h1, __int_as_float(p1.y), acc);
        acc = fmaf(h2, __int_as_float(p2.y), acc);
        acc = fmaf(h3, __int_as_float(p3.y), acc);
    }
    for (; i < end; ++i) {
        int2 p0 = epair[i];
        acc = fmaf(__half2float(u2[(size_t)p0.x * 16 + j]), __int_as_float(p0.y), acc);
    }
    float v = (j < 10) ? (acc + b[j]) : -1e30f;
    float m = v;
#pragma unroll
    for (int o = 8; o; o >>= 1) m = fmaxf(m, __shfl_xor(m, o, 64));
    float p = (j < 10) ? __expf(v - m) : 0.f;
    float s2 = p;
#pragma unroll
    for (int o = 8; o; o >>= 1) s2 += __shfl_xor(s2, o, 64);
    if (j < 10) out[(size_t)n * 10 + j] = p / s2;
}

extern "C" void kernel_launch(void* const* d_in, const int* in_sizes, int n_in,
                              void* d_out, int out_size, void* d_ws, size_t ws_size,
                              hipStream_t stream) {
    const float* x  = (const float*)d_in[0];
    const int*   ei = (const int*)d_in[1];
    const float* ew = (const float*)d_in[2];
    const float* W0 = (const float*)d_in[3];
    const float* b0 = (const float*)d_in[4];
    const float* W1 = (const float*)d_in[5];
    const float* b1 = (const float*)d_in[6];
    const float* W2 = (const float*)d_in[7];
    const float* b2 = (const float*)d_in[8];
    float* out = (float*)d_out;

    const int* src = ei;
    const int* dst = ei + NE;

    char* ws = (char*)d_ws;
    const size_t SZH = (size_t)NN * 64 * sizeof(__half);      // 6.4 MB
    __half* X16  = (__half*)ws;
    __half* H1   = (__half*)(ws + SZH);
    __half* H2   = (__half*)(ws + 2 * SZH);
    __half* U    = (__half*)(ws + 3 * SZH);                   // 1.6 MB
    int2*  epair = (int2*)(ws + 3 * SZH + (size_t)NN * 16 * 2);
    char*  tail  = ws + 3 * SZH + (size_t)NN * 16 * 2 + (size_t)NE * 8;
    int*   offs   = (int*)tail;
    int*   cursor = offs + (NN + 1);
    int*   bsum   = cursor + NN;

    const int gE   = (NE + 255) / 256;          // 3125
    const int gN   = (NN + 255) / 256;          // 196
    const int gC   = (NN * 32 + 255) / 256;     // 6250
    const int gF4  = (NN * 16 + 255) / 256;     // 3125 blocks: 4 waves x 4 nodes
    const int gN16 = (NN * 16 + 255) / 256;     // 3125

    // ----- CSR build + x cast -----
    hipMemsetAsync(cursor, 0, (size_t)NN * sizeof(int), stream);
    cast16_kernel<<<gC, 256, 0, stream>>>(x, X16);
    count_kernel<<<gE, 256, 0, stream>>>(dst, cursor);
    scan1_kernel<<<25, 256, 0, stream>>>(cursor, offs, bsum);
    scan3_kernel<<<gN, 256, 0, stream>>>(offs, bsum, cursor);
    scatter_kernel<<<gE, 256, 0, stream>>>(src, dst, ew, cursor, epair);

    // ----- layer 0: h1 = softmax(agg(x)@W0 + b0) -----
    fused4_kernel<<<gF4, 256, 0, stream>>>(X16, offs, epair, W0, b0, H1);

    // ----- layer 1: h2 = softmax(agg(h1)@W1 + b1) -----
    fused4_kernel<<<gF4, 256, 0, stream>>>(H1, offs, epair, W1, b1, H2);

    // ----- layer 2 linear: u2 = h2 @ W2 (64->10, pad 16) -----
    lin16h_kernel<<<gN16, 256, 0, stream>>>(H2, W2, U);

    // ----- layer 2: out = softmax(agg(u2) + b2) -----
    aggsm10h_kernel<<<gN16, 256, 0, stream>>>(U, offs, epair, b2, out);
}

// Round 14
// 264.292 us; speedup vs baseline: 2.3106x; 1.0570x over previous
//
#include <hip/hip_runtime.h>
#include <hip/hip_fp16.h>

#define NN 50000
#define NE 800000
#define NBUCK 196        // ceil(NN/256)
#define P1_EDGES 4096    // edges per pass-1 workgroup
#define P2_CAP 6144      // max edges per bucket (mean 4096, sigma ~64)

// ============ cast x (fp32) -> x16 (fp16), vectorized ============
__global__ __launch_bounds__(256) void cast16_kernel(const float* __restrict__ x,
                                                     __half* __restrict__ x16) {
    int i = blockIdx.x * 256 + threadIdx.x;
    if (i < NN * 32) {
        float2 v = reinterpret_cast<const float2*>(x)[i];
        reinterpret_cast<__half2*>(x16)[i] = __floats2half2_rn(v.x, v.y);
    }
}

// ============ CSR build: per-node degree count ============
__global__ __launch_bounds__(256) void count_kernel(const int* __restrict__ dst,
                                                    int* __restrict__ cnt) {
    int e = blockIdx.x * 256 + threadIdx.x;
    if (e < NE) atomicAdd(&cnt[dst[e]], 1);
}

__global__ __launch_bounds__(256) void scan1_kernel(const int* __restrict__ cnt,
                                                    int* __restrict__ offs,
                                                    int* __restrict__ bsum) {
    __shared__ int sm[256];
    int b = blockIdx.x, t = threadIdx.x;
    int base = b * 2048 + t * 8;
    int v[8];
    int s = 0;
#pragma unroll
    for (int i = 0; i < 8; ++i) {
        int idx = base + i;
        int c = (idx < NN) ? cnt[idx] : 0;
        v[i] = s;
        s += c;
    }
    sm[t] = s;
    __syncthreads();
    for (int off = 1; off < 256; off <<= 1) {
        int y = (t >= off) ? sm[t - off] : 0;
        __syncthreads();
        sm[t] += y;
        __syncthreads();
    }
    int excl = sm[t] - s;
#pragma unroll
    for (int i = 0; i < 8; ++i) {
        int idx = base + i;
        if (idx < NN) offs[idx] = excl + v[i];
    }
    if (t == 255) bsum[b] = sm[255];
}

// phase 2+3 merged: apply block offsets; also init the 196 bucket cursors
__global__ __launch_bounds__(256) void scan3_kernel(int* __restrict__ offs,
                                                    const int* __restrict__ bsum,
                                                    int* __restrict__ gcursor) {
    __shared__ int sb[32];
    if (threadIdx.x == 0) {
        int run = 0;
        for (int k = 0; k < 25; ++k) {
            sb[k] = run;
            run += bsum[k];
        }
    }
    __syncthreads();
    int i = blockIdx.x * 256 + threadIdx.x;
    if (i < NN) {
        int v = offs[i] + sb[i >> 11];
        offs[i] = v;
        if ((i & 255) == 0) gcursor[i >> 8] = v;  // bucket base
    }
    if (i == 0) offs[NN] = NE;
}

// ============ pass 1: LDS counting-sort a 4096-edge chunk by bucket (dst>>8),
// write each bucket-run to a claimed contiguous region (coalesced full lines) ====
__global__ __launch_bounds__(256) void sortp1_kernel(const int* __restrict__ src,
                                                     const int* __restrict__ dst,
                                                     const float* __restrict__ ew,
                                                     int* __restrict__ gcursor,
                                                     int2* __restrict__ epairT) {
    __shared__ int hist[256];      // counts -> cursors
    __shared__ int binBase[256];   // local exclusive scan
    __shared__ int gBase[256];     // claimed global base per bucket
    __shared__ int scanTmp[256];
    __shared__ int2 buf[P1_EDGES];
    __shared__ unsigned char bb[P1_EDGES];
    int tid = threadIdx.x;
    int e0 = blockIdx.x * P1_EDGES;
    int total = NE - e0;
    if (total > P1_EDGES) total = P1_EDGES;

    hist[tid] = 0;
    __syncthreads();
    // histogram by bucket
    for (int r = 0; r < 16; ++r) {
        int e = e0 + r * 256 + tid;
        if (e < NE) atomicAdd(&hist[dst[e] >> 8], 1);
    }
    __syncthreads();
    // exclusive scan of 256 bins
    int v = hist[tid];
    scanTmp[tid] = v;
    __syncthreads();
    for (int off = 1; off < 256; off <<= 1) {
        int y = (tid >= off) ? scanTmp[tid - off] : 0;
        __syncthreads();
        scanTmp[tid] += y;
        __syncthreads();
    }
    int excl = scanTmp[tid] - v;
    binBase[tid] = excl;
    hist[tid] = excl;  // becomes running cursor
    __syncthreads();
    // scatter into sorted LDS order (re-read edge data; L2-hot)
    for (int r = 0; r < 16; ++r) {
        int e = e0 + r * 256 + tid;
        if (e < NE) {
            int d = dst[e];
            int bk = d >> 8;
            int slot = atomicAdd(&hist[bk], 1);
            buf[slot] = make_int2(src[e] | ((d & 255) << 16), __float_as_int(ew[e]));
            bb[slot] = (unsigned char)bk;
        }
    }
    __syncthreads();
    // claim global space per bucket
    int c = hist[tid] - binBase[tid];
    gBase[tid] = (c > 0) ? atomicAdd(&gcursor[tid], c) : 0;
    __syncthreads();
    // write runs out: consecutive threads in a run -> consecutive addresses
    for (int i = tid; i < total; i += 256) {
        int bk = bb[i];
        epairT[gBase[bk] + (i - binBase[bk])] = buf[i];
    }
}

// ============ pass 2: per-bucket LDS counting-sort by exact node, sequential write ====
__global__ __launch_bounds__(256) void sortp2_kernel(const int2* __restrict__ epairT,
                                                     const int* __restrict__ offs,
                                                     int2* __restrict__ epair) {
    __shared__ int hist[256];
    __shared__ int scanTmp[256];
    __shared__ int2 buf[P2_CAP];
    int tid = threadIdx.x;
    int b = blockIdx.x;
    int n0 = b << 8;
    int nEnd = n0 + 256;
    if (nEnd > NN) nEnd = NN;
    int base = offs[n0];
    int total = offs[nEnd] - base;

    hist[tid] = 0;
    __syncthreads();
    for (int i = tid; i < total; i += 256) {
        int2 q = epairT[base + i];
        atomicAdd(&hist[(q.x >> 16) & 255], 1);
    }
    __syncthreads();
    int v = hist[tid];
    scanTmp[tid] = v;
    __syncthreads();
    for (int off = 1; off < 256; off <<= 1) {
        int y = (tid >= off) ? scanTmp[tid - off] : 0;
        __syncthreads();
        scanTmp[tid] += y;
        __syncthreads();
    }
    hist[tid] = scanTmp[tid] - v;  // exclusive scan -> cursor
    __syncthreads();
    for (int i = tid; i < total; i += 256) {
        int2 q = epairT[base + i];
        int slot = atomicAdd(&hist[(q.x >> 16) & 255], 1);
        buf[slot] = make_int2(q.x & 0xFFFF, q.y);
    }
    __syncthreads();
    for (int i = tid; i < total; i += 256) epair[base + i] = buf[i];
}

// ============ fused 64-dim layer, 4 nodes per wave, scalar-pipe gather ============
__global__ __launch_bounds__(256) void fused4_kernel(const __half* __restrict__ h,
                                                     const int* __restrict__ offs,
                                                     const int2* __restrict__ epair,
                                                     const float* __restrict__ W,
                                                     const float* __restrict__ b,
                                                     __half* __restrict__ out) {
    __shared__ float Wl[4096];  // 16 KB
    int tid = threadIdx.x;
    for (int i = tid; i < 1024; i += 256)
        reinterpret_cast<float4*>(Wl)[i] = reinterpret_cast<const float4*>(W)[i];
    __syncthreads();

    int lane = tid & 63;
    int wid = (blockIdx.x * 256 + tid) >> 6;
    int n0 = wid * 4;
    if (n0 >= NN) return;

    float av[4];
#pragma unroll
    for (int m = 0; m < 4; ++m) {
        int n = n0 + m;
        int beg = __builtin_amdgcn_readfirstlane(offs[n]);
        int end = __builtin_amdgcn_readfirstlane(offs[n + 1]);
        float a = 0.f;
        int i = beg;
        for (; i + 7 < end; i += 8) {
            int2 q0 = epair[i + 0], q1 = epair[i + 1], q2 = epair[i + 2], q3 = epair[i + 3];
            int2 q4 = epair[i + 4], q5 = epair[i + 5], q6 = epair[i + 6], q7 = epair[i + 7];
            int s0 = __builtin_amdgcn_readfirstlane(q0.x);
            int s1 = __builtin_amdgcn_readfirstlane(q1.x);
            int s2 = __builtin_amdgcn_readfirstlane(q2.x);
            int s3 = __builtin_amdgcn_readfirstlane(q3.x);
            int s4 = __builtin_amdgcn_readfirstlane(q4.x);
            int s5 = __builtin_amdgcn_readfirstlane(q5.x);
            int s6 = __builtin_amdgcn_readfirstlane(q6.x);
            int s7 = __builtin_amdgcn_readfirstlane(q7.x);
            float h0 = __half2float(h[((size_t)s0 << 6) + lane]);
            float h1 = __half2float(h[((size_t)s1 << 6) + lane]);
            float h2 = __half2float(h[((size_t)s2 << 6) + lane]);
            float h3 = __half2float(h[((size_t)s3 << 6) + lane]);
            float h4 = __half2float(h[((size_t)s4 << 6) + lane]);
            float h5 = __half2float(h[((size_t)s5 << 6) + lane]);
            float h6 = __half2float(h[((size_t)s6 << 6) + lane]);
            float h7 = __half2float(h[((size_t)s7 << 6) + lane]);
            a = fmaf(h0, __int_as_float(__builtin_amdgcn_readfirstlane(q0.y)), a);
            a = fmaf(h1, __int_as_float(__builtin_amdgcn_readfirstlane(q1.y)), a);
            a = fmaf(h2, __int_as_float(__builtin_amdgcn_readfirstlane(q2.y)), a);
            a = fmaf(h3, __int_as_float(__builtin_amdgcn_readfirstlane(q3.y)), a);
            a = fmaf(h4, __int_as_float(__builtin_amdgcn_readfirstlane(q4.y)), a);
            a = fmaf(h5, __int_as_float(__builtin_amdgcn_readfirstlane(q5.y)), a);
            a = fmaf(h6, __int_as_float(__builtin_amdgcn_readfirstlane(q6.y)), a);
            a = fmaf(h7, __int_as_float(__builtin_amdgcn_readfirstlane(q7.y)), a);
        }
        for (; i < end; ++i) {
            int2 q = epair[i];
            int s = __builtin_amdgcn_readfirstlane(q.x);
            float w = __int_as_float(__builtin_amdgcn_readfirstlane(q.y));
            a = fmaf(__half2float(h[((size_t)s << 6) + lane]), w, a);
        }
        av[m] = a;
    }

    int i0 = __float_as_int(av[0]), i1 = __float_as_int(av[1]);
    int i2 = __float_as_int(av[2]), i3 = __float_as_int(av[3]);
    float y0 = 0.f, y1 = 0.f, y2 = 0.f, y3 = 0.f;
#pragma unroll
    for (int k = 0; k < 64; ++k) {
        float w = Wl[k * 64 + lane];
        y0 = fmaf(__int_as_float(__builtin_amdgcn_readlane(i0, k)), w, y0);
        y1 = fmaf(__int_as_float(__builtin_amdgcn_readlane(i1, k)), w, y1);
        y2 = fmaf(__int_as_float(__builtin_amdgcn_readlane(i2, k)), w, y2);
        y3 = fmaf(__int_as_float(__builtin_amdgcn_readlane(i3, k)), w, y3);
    }
    float bl = b[lane];
    y0 += bl; y1 += bl; y2 += bl; y3 += bl;

#pragma unroll
    for (int m = 0; m < 4; ++m) {
        float y = (m == 0) ? y0 : (m == 1) ? y1 : (m == 2) ? y2 : y3;
        float mx = y;
#pragma unroll
        for (int o = 32; o; o >>= 1) mx = fmaxf(mx, __shfl_xor(mx, o, 64));
        float p = __expf(y - mx);
        float s2 = p;
#pragma unroll
        for (int o = 32; o; o >>= 1) s2 += __shfl_xor(s2, o, 64);
        out[(size_t)(n0 + m) * 64 + lane] = __float2half_rn(p / s2);
    }
}

// ============ linear 64 -> 10 (fp16 in, fp16 out, padded stride 16) ============
__global__ __launch_bounds__(256) void lin16h_kernel(const __half* __restrict__ H,
                                                     const float* __restrict__ W2,
                                                     __half* __restrict__ out) {
    int g = blockIdx.x * 256 + threadIdx.x;
    int n = g >> 4, j = g & 15;
    if (n >= NN) return;
    float acc = 0.f;
    if (j < 10) {
        const __half* hrow = H + (size_t)n * 64;
#pragma unroll
        for (int k = 0; k < 64; ++k) acc += __half2float(hrow[k]) * W2[k * 10 + j];
    }
    out[(size_t)n * 16 + j] = __float2half_rn(acc);
}

// ============ final: out = softmax(agg(u2) + b2), 10 classes ============
__global__ __launch_bounds__(256) void aggsm10h_kernel(const __half* __restrict__ u2,
                                                       const int* __restrict__ offs,
                                                       const int2* __restrict__ epair,
                                                       const float* __restrict__ b,
                                                       float* __restrict__ out) {
    int g = blockIdx.x * 256 + threadIdx.x;
    int n = g >> 4, j = g & 15;
    if (n >= NN) return;
    int beg = offs[n], end = offs[n + 1];
    float acc = 0.f;
    int i = beg;
    for (; i + 3 < end; i += 4) {
        int2 p0 = epair[i], p1 = epair[i + 1], p2 = epair[i + 2], p3 = epair[i + 3];
        float h0 = __half2float(u2[(size_t)p0.x * 16 + j]);
        float h1 = __half2float(u2[(size_t)p1.x * 16 + j]);
        float h2 = __half2float(u2[(size_t)p2.x * 16 + j]);
        float h3 = __half2float(u2[(size_t)p3.x * 16 + j]);
        acc = fmaf(h0, __int_as_float(p0.y), acc);
        acc = fmaf(h1, __int_as_float(p1.y), acc);
        acc = fmaf(h2, __int_as_float(p2.y), acc);
        acc = fmaf(h3, __int_as_float(p3.y), acc);
    }
    for (; i < end; ++i) {
        int2 p0 = epair[i];
        acc = fmaf(__half2float(u2[(size_t)p0.x * 16 + j]), __int_as_float(p0.y), acc);
    }
    float v = (j < 10) ? (acc + b[j]) : -1e30f;
    float m = v;
#pragma unroll
    for (int o = 8; o; o >>= 1) m = fmaxf(m, __shfl_xor(m, o, 64));
    float p = (j < 10) ? __expf(v - m) : 0.f;
    float s2 = p;
#pragma unroll
    for (int o = 8; o; o >>= 1) s2 += __shfl_xor(s2, o, 64);
    if (j < 10) out[(size_t)n * 10 + j] = p / s2;
}

extern "C" void kernel_launch(void* const* d_in, const int* in_sizes, int n_in,
                              void* d_out, int out_size, void* d_ws, size_t ws_size,
                              hipStream_t stream) {
    const float* x  = (const float*)d_in[0];
    const int*   ei = (const int*)d_in[1];
    const float* ew = (const float*)d_in[2];
    const float* W0 = (const float*)d_in[3];
    const float* b0 = (const float*)d_in[4];
    const float* W1 = (const float*)d_in[5];
    const float* b1 = (const float*)d_in[6];
    const float* W2 = (const float*)d_in[7];
    const float* b2 = (const float*)d_in[8];
    float* out = (float*)d_out;

    const int* src = ei;
    const int* dst = ei + NE;

    char* ws = (char*)d_ws;
    const size_t SZH = (size_t)NN * 64 * sizeof(__half);      // 6.4 MB
    __half* X16   = (__half*)ws;
    __half* H1    = (__half*)(ws + SZH);
    __half* H2    = (__half*)(ws + 2 * SZH);
    __half* U     = (__half*)(ws + 3 * SZH);                  // 1.6 MB
    int2*  epair  = (int2*)(ws + 3 * SZH + (size_t)NN * 16 * 2);       // 6.4 MB
    int2*  epairT = (int2*)(ws + 3 * SZH + (size_t)NN * 16 * 2 + (size_t)NE * 8); // 6.4 MB
    char*  tail   = ws + 3 * SZH + (size_t)NN * 16 * 2 + 2 * (size_t)NE * 8;
    int*   offs    = (int*)tail;          // (NN+1)*4
    int*   cnt     = offs + (NN + 1);     // NN*4
    int*   bsum    = cnt + NN;            // 32*4
    int*   gcursor = bsum + 32;           // 256*4

    const int gE   = (NE + 255) / 256;          // 3125
    const int gN   = (NN + 255) / 256;          // 196
    const int gC   = (NN * 32 + 255) / 256;     // 6250
    const int gF4  = (NN * 16 + 255) / 256;     // 3125
    const int gN16 = (NN * 16 + 255) / 256;     // 3125
    const int gP1  = (NE + P1_EDGES - 1) / P1_EDGES;  // 196

    // ----- CSR build + x cast -----
    hipMemsetAsync(cnt, 0, (size_t)NN * sizeof(int), stream);
    cast16_kernel<<<gC, 256, 0, stream>>>(x, X16);
    count_kernel<<<gE, 256, 0, stream>>>(dst, cnt);
    scan1_kernel<<<25, 256, 0, stream>>>(cnt, offs, bsum);
    scan3_kernel<<<gN, 256, 0, stream>>>(offs, bsum, gcursor);
    sortp1_kernel<<<gP1, 256, 0, stream>>>(src, dst, ew, gcursor, epairT);
    sortp2_kernel<<<NBUCK, 256, 0, stream>>>(epairT, offs, epair);

    // ----- layer 0: h1 = softmax(agg(x)@W0 + b0) -----
    fused4_kernel<<<gF4, 256, 0, stream>>>(X16, offs, epair, W0, b0, H1);

    // ----- layer 1: h2 = softmax(agg(h1)@W1 + b1) -----
    fused4_kernel<<<gF4, 256, 0, stream>>>(H1, offs, epair, W1, b1, H2);

    // ----- layer 2 linear: u2 = h2 @ W2 (64->10, pad 16) -----
    lin16h_kernel<<<gN16, 256, 0, stream>>>(H2, W2, U);

    // ----- layer 2: out = softmax(agg(u2) + b2) -----
    aggsm10h_kernel<<<gN16, 256, 0, stream>>>(U, offs, epair, b2, out);
}

// Round 15
// 223.290 us; speedup vs baseline: 2.7349x; 1.1836x over previous
//
#include <hip/hip_runtime.h>
#include <hip/hip_fp16.h>

#define NN 50000
#define NE 800000
#define NBUCK 196        // ceil(NN/256)
#define P1_EDGES 4096    // edges per pass-1 workgroup
#define P2_CAP 6144      // max edges per bucket (mean 4096, sigma ~64)

// ============ cast x (fp32) -> x16 (fp16), vectorized ============
__global__ __launch_bounds__(256) void cast16_kernel(const float* __restrict__ x,
                                                     __half* __restrict__ x16) {
    int i = blockIdx.x * 256 + threadIdx.x;
    if (i < NN * 32) {
        float2 v = reinterpret_cast<const float2*>(x)[i];
        reinterpret_cast<__half2*>(x16)[i] = __floats2half2_rn(v.x, v.y);
    }
}

// ============ bucket histogram (196 buckets of 256 nodes), LDS-aggregated ============
__global__ __launch_bounds__(256) void countB_kernel(const int* __restrict__ dst,
                                                     int* __restrict__ gcnt) {
    __shared__ int hist[256];
    int tid = threadIdx.x;
    hist[tid] = 0;
    __syncthreads();
    int e0 = blockIdx.x * P1_EDGES;
    for (int r = 0; r < 16; ++r) {
        int e = e0 + r * 256 + tid;
        if (e < NE) atomicAdd(&hist[dst[e] >> 8], 1);
    }
    __syncthreads();
    int c = hist[tid];
    if (c) atomicAdd(&gcnt[tid], c);
}

// ============ scan of 196 bucket totals -> bases + cursors ============
__global__ __launch_bounds__(256) void scanB_kernel(const int* __restrict__ gcnt,
                                                    int* __restrict__ gbase,
                                                    int* __restrict__ gcursor) {
    __shared__ int sm[256];
    int t = threadIdx.x;
    int v = (t < NBUCK) ? gcnt[t] : 0;
    sm[t] = v;
    __syncthreads();
    for (int off = 1; off < 256; off <<= 1) {
        int y = (t >= off) ? sm[t - off] : 0;
        __syncthreads();
        sm[t] += y;
        __syncthreads();
    }
    int excl = sm[t] - v;
    if (t < NBUCK) {
        gbase[t] = excl;
        gcursor[t] = excl;
    }
    if (t == 0) gbase[NBUCK] = NE;
}

// ============ pass 1: LDS counting-sort 4096-edge chunk by bucket, coalesced runs out ====
__global__ __launch_bounds__(256) void sortp1_kernel(const int* __restrict__ src,
                                                     const int* __restrict__ dst,
                                                     const float* __restrict__ ew,
                                                     int* __restrict__ gcursor,
                                                     int2* __restrict__ epairT) {
    __shared__ int hist[256];
    __shared__ int binBase[256];
    __shared__ int gBase[256];
    __shared__ int scanTmp[256];
    __shared__ int2 buf[P1_EDGES];
    __shared__ unsigned char bb[P1_EDGES];
    int tid = threadIdx.x;
    int e0 = blockIdx.x * P1_EDGES;
    int total = NE - e0;
    if (total > P1_EDGES) total = P1_EDGES;

    hist[tid] = 0;
    __syncthreads();
    for (int r = 0; r < 16; ++r) {
        int e = e0 + r * 256 + tid;
        if (e < NE) atomicAdd(&hist[dst[e] >> 8], 1);
    }
    __syncthreads();
    int v = hist[tid];
    scanTmp[tid] = v;
    __syncthreads();
    for (int off = 1; off < 256; off <<= 1) {
        int y = (tid >= off) ? scanTmp[tid - off] : 0;
        __syncthreads();
        scanTmp[tid] += y;
        __syncthreads();
    }
    int excl = scanTmp[tid] - v;
    binBase[tid] = excl;
    hist[tid] = excl;
    __syncthreads();
    for (int r = 0; r < 16; ++r) {
        int e = e0 + r * 256 + tid;
        if (e < NE) {
            int d = dst[e];
            int bk = d >> 8;
            int slot = atomicAdd(&hist[bk], 1);
            buf[slot] = make_int2(src[e] | ((d & 255) << 16), __float_as_int(ew[e]));
            bb[slot] = (unsigned char)bk;
        }
    }
    __syncthreads();
    int c = hist[tid] - binBase[tid];
    gBase[tid] = (c > 0) ? atomicAdd(&gcursor[tid], c) : 0;
    __syncthreads();
    for (int i = tid; i < total; i += 256) {
        int bk = bb[i];
        epairT[gBase[bk] + (i - binBase[bk])] = buf[i];
    }
}

// ============ pass 2: per-bucket sort by node; computes & writes offs[]; packs 4B ====
__global__ __launch_bounds__(256) void sortp2_kernel(const int2* __restrict__ epairT,
                                                     const int* __restrict__ gbase,
                                                     int* __restrict__ offs,
                                                     int* __restrict__ epair) {
    __shared__ int hist[256];
    __shared__ int scanTmp[256];
    __shared__ int buf[P2_CAP];
    int tid = threadIdx.x;
    int b = blockIdx.x;
    int base = gbase[b];
    int total = gbase[b + 1] - base;

    hist[tid] = 0;
    __syncthreads();
    for (int i = tid; i < total; i += 256) {
        int2 q = epairT[base + i];
        atomicAdd(&hist[(q.x >> 16) & 255], 1);
    }
    __syncthreads();
    int v = hist[tid];
    scanTmp[tid] = v;
    __syncthreads();
    for (int off = 1; off < 256; off <<= 1) {
        int y = (tid >= off) ? scanTmp[tid - off] : 0;
        __syncthreads();
        scanTmp[tid] += y;
        __syncthreads();
    }
    int excl = scanTmp[tid] - v;
    int n = (b << 8) + tid;
    if (n < NN) offs[n] = base + excl;
    if (b == NBUCK - 1 && tid == 0) offs[NN] = NE;
    hist[tid] = excl;
    __syncthreads();
    for (int i = tid; i < total; i += 256) {
        int2 q = epairT[base + i];
        int slot = atomicAdd(&hist[(q.x >> 16) & 255], 1);
        unsigned short wh = __half_as_ushort(__float2half_rn(__int_as_float(q.y)));
        buf[slot] = (q.x & 0xFFFF) | ((int)wh << 16);
    }
    __syncthreads();
    for (int i = tid; i < total; i += 256) epair[base + i] = buf[i];
}

// ============ fused 64-dim layer, 4 nodes per wave, scalar-pipe gather ============
// epair entry: src(16b) | w_fp16(16b). All per-edge metadata wave-uniform.
__global__ __launch_bounds__(256) void fused4_kernel(const __half* __restrict__ h,
                                                     const int* __restrict__ offs,
                                                     const int* __restrict__ epair,
                                                     const float* __restrict__ W,
                                                     const float* __restrict__ b,
                                                     __half* __restrict__ out) {
    __shared__ float Wl[4096];  // 16 KB
    int tid = threadIdx.x;
    for (int i = tid; i < 1024; i += 256)
        reinterpret_cast<float4*>(Wl)[i] = reinterpret_cast<const float4*>(W)[i];
    __syncthreads();

    int lane = tid & 63;
    int wid = (blockIdx.x * 256 + tid) >> 6;
    int n0 = wid * 4;
    if (n0 >= NN) return;

    float av[4];
#pragma unroll
    for (int m = 0; m < 4; ++m) {
        int n = n0 + m;
        int beg = __builtin_amdgcn_readfirstlane(offs[n]);
        int end = __builtin_amdgcn_readfirstlane(offs[n + 1]);
        float a = 0.f;
        int i = beg;
        for (; i + 7 < end; i += 8) {
            int u0 = __builtin_amdgcn_readfirstlane(epair[i + 0]);
            int u1 = __builtin_amdgcn_readfirstlane(epair[i + 1]);
            int u2 = __builtin_amdgcn_readfirstlane(epair[i + 2]);
            int u3 = __builtin_amdgcn_readfirstlane(epair[i + 3]);
            int u4 = __builtin_amdgcn_readfirstlane(epair[i + 4]);
            int u5 = __builtin_amdgcn_readfirstlane(epair[i + 5]);
            int u6 = __builtin_amdgcn_readfirstlane(epair[i + 6]);
            int u7 = __builtin_amdgcn_readfirstlane(epair[i + 7]);
            float h0 = __half2float(h[((size_t)(u0 & 0xFFFF) << 6) + lane]);
            float h1 = __half2float(h[((size_t)(u1 & 0xFFFF) << 6) + lane]);
            float h2 = __half2float(h[((size_t)(u2 & 0xFFFF) << 6) + lane]);
            float h3 = __half2float(h[((size_t)(u3 & 0xFFFF) << 6) + lane]);
            float h4 = __half2float(h[((size_t)(u4 & 0xFFFF) << 6) + lane]);
            float h5 = __half2float(h[((size_t)(u5 & 0xFFFF) << 6) + lane]);
            float h6 = __half2float(h[((size_t)(u6 & 0xFFFF) << 6) + lane]);
            float h7 = __half2float(h[((size_t)(u7 & 0xFFFF) << 6) + lane]);
            a = fmaf(h0, __half2float(__ushort_as_half((unsigned short)(u0 >> 16))), a);
            a = fmaf(h1, __half2float(__ushort_as_half((unsigned short)(u1 >> 16))), a);
            a = fmaf(h2, __half2float(__ushort_as_half((unsigned short)(u2 >> 16))), a);
            a = fmaf(h3, __half2float(__ushort_as_half((unsigned short)(u3 >> 16))), a);
            a = fmaf(h4, __half2float(__ushort_as_half((unsigned short)(u4 >> 16))), a);
            a = fmaf(h5, __half2float(__ushort_as_half((unsigned short)(u5 >> 16))), a);
            a = fmaf(h6, __half2float(__ushort_as_half((unsigned short)(u6 >> 16))), a);
            a = fmaf(h7, __half2float(__ushort_as_half((unsigned short)(u7 >> 16))), a);
        }
        for (; i < end; ++i) {
            int u = __builtin_amdgcn_readfirstlane(epair[i]);
            float hw = __half2float(__ushort_as_half((unsigned short)(u >> 16)));
            a = fmaf(__half2float(h[((size_t)(u & 0xFFFF) << 6) + lane]), hw, a);
        }
        av[m] = a;
    }

    int i0 = __float_as_int(av[0]), i1 = __float_as_int(av[1]);
    int i2 = __float_as_int(av[2]), i3 = __float_as_int(av[3]);
    float y0 = 0.f, y1 = 0.f, y2 = 0.f, y3 = 0.f;
#pragma unroll
    for (int k = 0; k < 64; ++k) {
        float w = Wl[k * 64 + lane];
        y0 = fmaf(__int_as_float(__builtin_amdgcn_readlane(i0, k)), w, y0);
        y1 = fmaf(__int_as_float(__builtin_amdgcn_readlane(i1, k)), w, y1);
        y2 = fmaf(__int_as_float(__builtin_amdgcn_readlane(i2, k)), w, y2);
        y3 = fmaf(__int_as_float(__builtin_amdgcn_readlane(i3, k)), w, y3);
    }
    float bl = b[lane];
    y0 += bl; y1 += bl; y2 += bl; y3 += bl;

#pragma unroll
    for (int m = 0; m < 4; ++m) {
        float y = (m == 0) ? y0 : (m == 1) ? y1 : (m == 2) ? y2 : y3;
        float mx = y;
#pragma unroll
        for (int o = 32; o; o >>= 1) mx = fmaxf(mx, __shfl_xor(mx, o, 64));
        float p = __expf(y - mx);
        float s2 = p;
#pragma unroll
        for (int o = 32; o; o >>= 1) s2 += __shfl_xor(s2, o, 64);
        out[(size_t)(n0 + m) * 64 + lane] = __float2half_rn(p / s2);
    }
}

// ============ linear 64 -> 10 (fp16 in, fp16 out, padded stride 16) ============
__global__ __launch_bounds__(256) void lin16h_kernel(const __half* __restrict__ H,
                                                     const float* __restrict__ W2,
                                                     __half* __restrict__ out) {
    int g = blockIdx.x * 256 + threadIdx.x;
    int n = g >> 4, j = g & 15;
    if (n >= NN) return;
    float acc = 0.f;
    if (j < 10) {
        const __half* hrow = H + (size_t)n * 64;
#pragma unroll
        for (int k = 0; k < 64; ++k) acc += __half2float(hrow[k]) * W2[k * 10 + j];
    }
    out[(size_t)n * 16 + j] = __float2half_rn(acc);
}

// ============ final: out = softmax(agg(u2) + b2), 10 classes ============
__global__ __launch_bounds__(256) void aggsm10h_kernel(const __half* __restrict__ u2,
                                                       const int* __restrict__ offs,
                                                       const int* __restrict__ epair,
                                                       const float* __restrict__ b,
                                                       float* __restrict__ out) {
    int g = blockIdx.x * 256 + threadIdx.x;
    int n = g >> 4, j = g & 15;
    if (n >= NN) return;
    int beg = offs[n], end = offs[n + 1];
    float acc = 0.f;
    int i = beg;
    for (; i + 3 < end; i += 4) {
        int q0 = epair[i], q1 = epair[i + 1], q2 = epair[i + 2], q3 = epair[i + 3];
        float h0 = __half2float(u2[(size_t)(q0 & 0xFFFF) * 16 + j]);
        float h1 = __half2float(u2[(size_t)(q1 & 0xFFFF) * 16 + j]);
        float h2 = __half2float(u2[(size_t)(q2 & 0xFFFF) * 16 + j]);
        float h3 = __half2float(u2[(size_t)(q3 & 0xFFFF) * 16 + j]);
        acc = fmaf(h0, __half2float(__ushort_as_half((unsigned short)(q0 >> 16))), acc);
        acc = fmaf(h1, __half2float(__ushort_as_half((unsigned short)(q1 >> 16))), acc);
        acc = fmaf(h2, __half2float(__ushort_as_half((unsigned short)(q2 >> 16))), acc);
        acc = fmaf(h3, __half2float(__ushort_as_half((unsigned short)(q3 >> 16))), acc);
    }
    for (; i < end; ++i) {
        int q = epair[i];
        acc = fmaf(__half2float(u2[(size_t)(q & 0xFFFF) * 16 + j]),
                   __half2float(__ushort_as_half((unsigned short)(q >> 16))), acc);
    }
    float v = (j < 10) ? (acc + b[j]) : -1e30f;
    float m = v;
#pragma unroll
    for (int o = 8; o; o >>= 1) m = fmaxf(m, __shfl_xor(m, o, 64));
    float p = (j < 10) ? __expf(v - m) : 0.f;
    float s2 = p;
#pragma unroll
    for (int o = 8; o; o >>= 1) s2 += __shfl_xor(s2, o, 64);
    if (j < 10) out[(size_t)n * 10 + j] = p / s2;
}

extern "C" void kernel_launch(void* const* d_in, const int* in_sizes, int n_in,
                              void* d_out, int out_size, void* d_ws, size_t ws_size,
                              hipStream_t stream) {
    const float* x  = (const float*)d_in[0];
    const int*   ei = (const int*)d_in[1];
    const float* ew = (const float*)d_in[2];
    const float* W0 = (const float*)d_in[3];
    const float* b0 = (const float*)d_in[4];
    const float* W1 = (const float*)d_in[5];
    const float* b1 = (const float*)d_in[6];
    const float* W2 = (const float*)d_in[7];
    const float* b2 = (const float*)d_in[8];
    float* out = (float*)d_out;

    const int* src = ei;
    const int* dst = ei + NE;

    char* ws = (char*)d_ws;
    const size_t SZH = (size_t)NN * 64 * sizeof(__half);      // 6.4 MB
    __half* X16   = (__half*)ws;
    __half* H1    = (__half*)(ws + SZH);
    __half* H2    = (__half*)(ws + 2 * SZH);
    __half* U     = (__half*)(ws + 3 * SZH);                  // 1.6 MB
    int*   epair  = (int*)(ws + 3 * SZH + (size_t)NN * 16 * 2);          // 3.2 MB
    int2*  epairT = (int2*)(ws + 3 * SZH + (size_t)NN * 16 * 2 + (size_t)NE * 4); // 6.4 MB
    char*  tail   = ws + 3 * SZH + (size_t)NN * 16 * 2 + (size_t)NE * 4 + (size_t)NE * 8;
    int*   offs    = (int*)tail;          // (NN+1)*4
    int*   gcnt    = offs + (NN + 1);     // 256*4
    int*   gbase   = gcnt + 256;          // (NBUCK+1)*4
    int*   gcursor = gbase + (NBUCK + 1); // 256*4

    const int gC   = (NN * 32 + 255) / 256;     // 6250
    const int gF4  = (NN * 16 + 255) / 256;     // 3125
    const int gN16 = (NN * 16 + 255) / 256;     // 3125
    const int gP1  = (NE + P1_EDGES - 1) / P1_EDGES;  // 196

    // ----- CSR build (bucketed) + x cast -----
    hipMemsetAsync(gcnt, 0, 256 * sizeof(int), stream);
    cast16_kernel<<<gC, 256, 0, stream>>>(x, X16);
    countB_kernel<<<gP1, 256, 0, stream>>>(dst, gcnt);
    scanB_kernel<<<1, 256, 0, stream>>>(gcnt, gbase, gcursor);
    sortp1_kernel<<<gP1, 256, 0, stream>>>(src, dst, ew, gcursor, epairT);
    sortp2_kernel<<<NBUCK, 256, 0, stream>>>(epairT, gbase, offs, epair);

    // ----- layer 0: h1 = softmax(agg(x)@W0 + b0) -----
    fused4_kernel<<<gF4, 256, 0, stream>>>(X16, offs, epair, W0, b0, H1);

    // ----- layer 1: h2 = softmax(agg(h1)@W1 + b1) -----
    fused4_kernel<<<gF4, 256, 0, stream>>>(H1, offs, epair, W1, b1, H2);

    // ----- layer 2 linear: u2 = h2 @ W2 (64->10, pad 16) -----
    lin16h_kernel<<<gN16, 256, 0, stream>>>(H2, W2, U);

    // ----- layer 2: out = softmax(agg(u2) + b2) -----
    aggsm10h_kernel<<<gN16, 256, 0, stream>>>(U, offs, epair, b2, out);
}